// Round 1
// baseline (3789.691 us; speedup 1.0000x reference)
//
#include <hip/hip_runtime.h>

// GraphSAGE 3-layer forward, MI355X.
// Strategy (round 1 baseline):
//   mean-aggregation is linear => aggregate transformed features:
//     sage(h) = (sum_{e:dst=n} y[src_e]) / max(cnt[n],1) + bl + h @ wr.T,  y = h @ wl.T
//   Per layer: GEMM(y) -> atomic scatter-add -> GEMM(wr path) with fused
//   epilogue (mean + bias + relu + dropout).
// Buffers rotate through 3 x N x 128 fp32 slabs in d_ws (+ cnt).

constexpr int N = 50000;
constexpr int E = 800000;
constexpr int K = 128;   // inner dim of every GEMM

__global__ void count_kernel(const int* __restrict__ dst, float* __restrict__ cnt) {
  int e = blockIdx.x * 256 + threadIdx.x;
  if (e < E) atomicAdd(&cnt[dst[e]], 1.0f);
}

// Scatter-add Y[src] into AGG[dst], D channels (D % 4 == 0).
template <int D>
__global__ __launch_bounds__(256) void scatter_kernel(
    const float* __restrict__ Y, float* __restrict__ AGG,
    const int* __restrict__ src, const int* __restrict__ dst) {
  constexpr unsigned C4 = D / 4;
  unsigned idx = blockIdx.x * 256u + threadIdx.x;
  unsigned e = idx / C4;
  unsigned c4 = idx % C4;
  if (e >= E) return;
  int s = src[e];
  int d = dst[e];
  float4 v = ((const float4*)(Y + (size_t)s * D))[c4];
  float* a = AGG + (size_t)d * D + c4 * 4;
  atomicAdd(a + 0, v.x);
  atomicAdd(a + 1, v.y);
  atomicAdd(a + 2, v.z);
  atomicAdd(a + 3, v.w);
}

// out[n,c] = dot(A[n,:], W[c,:])  (+ fused SAGE epilogue when EPI)
// A: N x K row-major. W: DOUT x K row-major (transposed into LDS).
// Each thread computes 2 rows x 4 consecutive cols.
template <int DOUT, bool EPI, bool RELU, bool DROP>
__global__ __launch_bounds__(256) void gemm_kernel(
    const float* __restrict__ A, const float* __restrict__ W,
    const float* __restrict__ bias, const float* __restrict__ AGG,
    const float* __restrict__ cnt, const float* __restrict__ U,
    float* __restrict__ out, int ntiles) {
  constexpr int CG = DOUT / 4;   // threads covering one row
  constexpr int RH = 256 / CG;   // half the rows per tile
  constexpr int ROWS = RH * 2;   // rows per tile
  __shared__ float Wt[K * DOUT];        // Wt[k*DOUT + c]
  __shared__ float Al[ROWS * K];

  // Stage W transposed (conflict-free b128 reads in the inner loop).
  for (int i = threadIdx.x; i < DOUT * (K / 4); i += 256) {
    int c = i / (K / 4);
    int k4 = i % (K / 4);
    float4 w = ((const float4*)W)[i];
    Wt[(k4 * 4 + 0) * DOUT + c] = w.x;
    Wt[(k4 * 4 + 1) * DOUT + c] = w.y;
    Wt[(k4 * 4 + 2) * DOUT + c] = w.z;
    Wt[(k4 * 4 + 3) * DOUT + c] = w.w;
  }

  const int r = threadIdx.x / CG;
  const int c0 = (threadIdx.x % CG) * 4;

  for (int t = blockIdx.x; t < ntiles; t += gridDim.x) {
    const int row0 = t * ROWS;
    __syncthreads();  // covers Wt (first iter) and Al reuse (later iters)
    for (int i = threadIdx.x; i < ROWS * (K / 4); i += 256) {
      int rr = i / (K / 4);
      int n = row0 + rr;
      float4 v = (n < N) ? ((const float4*)(A + (size_t)n * K))[i % (K / 4)]
                         : make_float4(0.f, 0.f, 0.f, 0.f);
      ((float4*)Al)[i] = v;
    }
    __syncthreads();

    float4 acc0 = make_float4(0.f, 0.f, 0.f, 0.f);
    float4 acc1 = make_float4(0.f, 0.f, 0.f, 0.f);
#pragma unroll 8
    for (int k = 0; k < K; ++k) {
      float a0 = Al[r * K + k];
      float a1 = Al[(r + RH) * K + k];
      float4 w = *(const float4*)&Wt[k * DOUT + c0];
      acc0.x += a0 * w.x; acc0.y += a0 * w.y;
      acc0.z += a0 * w.z; acc0.w += a0 * w.w;
      acc1.x += a1 * w.x; acc1.y += a1 * w.y;
      acc1.z += a1 * w.z; acc1.w += a1 * w.w;
    }

#pragma unroll
    for (int h = 0; h < 2; ++h) {
      int n = row0 + r + h * RH;
      if (n < N) {
        float4 acc = (h == 0) ? acc0 : acc1;
        size_t base = (size_t)n * DOUT + c0;
        if (EPI) {
          float inv = 1.0f / fmaxf(cnt[n], 1.0f);
          float4 g = *(const float4*)&AGG[base];
          float4 b = *(const float4*)&bias[c0];
          float4 v;
          v.x = g.x * inv + b.x + acc.x;
          v.y = g.y * inv + b.y + acc.y;
          v.z = g.z * inv + b.z + acc.z;
          v.w = g.w * inv + b.w + acc.w;
          if (RELU) {
            v.x = fmaxf(v.x, 0.f); v.y = fmaxf(v.y, 0.f);
            v.z = fmaxf(v.z, 0.f); v.w = fmaxf(v.w, 0.f);
          }
          if (DROP) {
            const float s = 1.0f / 0.7f;
            float4 u = *(const float4*)&U[base];
            v.x *= (u.x >= 0.3f) ? s : 0.f;
            v.y *= (u.y >= 0.3f) ? s : 0.f;
            v.z *= (u.z >= 0.3f) ? s : 0.f;
            v.w *= (u.w >= 0.3f) ? s : 0.f;
          }
          *(float4*)&out[base] = v;
        } else {
          *(float4*)&out[base] = acc;
        }
      }
    }
  }
}

extern "C" void kernel_launch(void* const* d_in, const int* in_sizes, int n_in,
                              void* d_out, int out_size, void* d_ws, size_t ws_size,
                              hipStream_t stream) {
  const float* x   = (const float*)d_in[0];
  const float* u1  = (const float*)d_in[1];
  const float* u2  = (const float*)d_in[2];
  const float* wl0 = (const float*)d_in[3];
  const float* bl0 = (const float*)d_in[4];
  const float* wr0 = (const float*)d_in[5];
  const float* wl1 = (const float*)d_in[6];
  const float* bl1 = (const float*)d_in[7];
  const float* wr1 = (const float*)d_in[8];
  const float* wl2 = (const float*)d_in[9];
  const float* bl2 = (const float*)d_in[10];
  const float* wr2 = (const float*)d_in[11];
  const int* edge  = (const int*)d_in[12];
  const int* src = edge;
  const int* dst = edge + E;
  float* out = (float*)d_out;

  float* B0 = (float*)d_ws;                 // N x 128
  float* B1 = B0 + (size_t)N * 128;         // N x 128
  float* B2 = B1 + (size_t)N * 128;         // N x 128
  float* cnt = B2 + (size_t)N * 128;        // N

  // d_ws is poisoned 0xAA before every call: zero what must start at 0.
  hipMemsetAsync(B1, 0, (size_t)N * 128 * sizeof(float), stream);
  hipMemsetAsync(B2, 0, (size_t)N * 128 * sizeof(float), stream);
  hipMemsetAsync(cnt, 0, (size_t)N * sizeof(float), stream);

  count_kernel<<<(E + 255) / 256, 256, 0, stream>>>(dst, cnt);

  const int GB = 512;                 // gemm grid (2 blocks/CU cap via LDS anyway)
  const int nt128 = (N + 15) / 16;    // ROWS=16 when DOUT=128
  const int nt64  = (N + 31) / 32;    // ROWS=32 when DOUT=64

  // ---- Layer 0: A = x ----
  gemm_kernel<128, false, false, false><<<GB, 256, 0, stream>>>(
      x, wl0, nullptr, nullptr, nullptr, nullptr, B0, nt128);          // Y0 = x@wl0.T
  scatter_kernel<128><<<(E * 32 + 255) / 256, 256, 0, stream>>>(B0, B1, src, dst);
  gemm_kernel<128, true, true, true><<<GB, 256, 0, stream>>>(
      x, wr0, bl0, B1, cnt, u1, B0, nt128);                            // h0 -> B0

  // ---- Layer 1: A = h0 (B0) ----
  gemm_kernel<128, false, false, false><<<GB, 256, 0, stream>>>(
      B0, wl1, nullptr, nullptr, nullptr, nullptr, B1, nt128);         // Y1 -> B1
  scatter_kernel<128><<<(E * 32 + 255) / 256, 256, 0, stream>>>(B1, B2, src, dst);
  gemm_kernel<128, true, true, true><<<GB, 256, 0, stream>>>(
      B0, wr1, bl1, B2, cnt, u2, B1, nt128);                           // h1 -> B1

  // ---- Layer 2: A = h1 (B1), DOUT=64 ----
  hipMemsetAsync(B0, 0, (size_t)N * 64 * sizeof(float), stream);       // AGG2
  gemm_kernel<64, false, false, false><<<GB, 256, 0, stream>>>(
      B1, wl2, nullptr, nullptr, nullptr, nullptr, B2, nt64);          // Y2 -> B2
  scatter_kernel<64><<<(E * 16 + 255) / 256, 256, 0, stream>>>(B2, B0, src, dst);
  gemm_kernel<64, true, false, false><<<GB, 256, 0, stream>>>(
      B1, wr2, bl2, B0, cnt, nullptr, out, nt64);                      // out
}

// Round 2
// 952.073 us; speedup vs baseline: 3.9805x; 3.9805x over previous
//
#include <hip/hip_runtime.h>

// GraphSAGE 3-layer forward, MI355X. Round 2:
//   Replace fp32 atomic scatter (2.7 ms of round-1's 3.79 ms; WRITE_SIZE
//   showed 1.6 GB/dispatch of L2 RMW traffic) with on-device CSR build +
//   gather-reduce fused into the epilogue GEMM. No feature atomics at all.
// Buffers: 2 x N x 128 fp32 slabs (h in-place, Y per layer) + CSR ints.

constexpr int N = 50000;
constexpr int E = 800000;
constexpr int K = 128;   // inner dim of every GEMM

// ---------------- CSR build ----------------

__global__ void hist_kernel(const int* __restrict__ dst, int* __restrict__ deg) {
  int e = blockIdx.x * 256 + threadIdx.x;
  if (e < E) atomicAdd(&deg[dst[e]], 1);
}

// Single-block exclusive scan over deg[N] -> offs[N+1]; also init cursor.
__global__ __launch_bounds__(1024) void scan_kernel(
    const int* __restrict__ deg, int* __restrict__ offs, int* __restrict__ cursor) {
  __shared__ int part[1024];
  const int t = threadIdx.x;
  const int chunk = (N + 1023) / 1024;
  const int lo = t * chunk;
  const int hi = min(lo + chunk, N);
  int s = 0;
  for (int i = lo; i < hi; ++i) s += deg[i];
  part[t] = s;
  __syncthreads();
  for (int off = 1; off < 1024; off <<= 1) {
    int v = (t >= off) ? part[t - off] : 0;
    __syncthreads();
    part[t] += v;
    __syncthreads();
  }
  int run = (t == 0) ? 0 : part[t - 1];
  for (int i = lo; i < hi; ++i) {
    offs[i] = run;
    cursor[i] = run;
    run += deg[i];
  }
  if (t == 1023) offs[N] = run;   // == E
}

__global__ void fill_kernel(const int* __restrict__ src, const int* __restrict__ dst,
                            int* __restrict__ cursor, int* __restrict__ elist) {
  int e = blockIdx.x * 256 + threadIdx.x;
  if (e < E) {
    int pos = atomicAdd(&cursor[dst[e]], 1);
    elist[pos] = src[e];
  }
}

// ---------------- wl GEMM: Y[n,c] = dot(A[n,:], W[c,:]) ----------------
template <int DOUT>
__global__ __launch_bounds__(256) void gemm_wl_kernel(
    const float* __restrict__ A, const float* __restrict__ W,
    float* __restrict__ out, int ntiles) {
  constexpr int CG = DOUT / 4;   // threads covering one row
  constexpr int RH = 256 / CG;
  constexpr int ROWS = RH * 2;
  __shared__ float Wt[K * DOUT];   // Wt[k*DOUT + c]
  __shared__ float Al[ROWS * K];

  for (int i = threadIdx.x; i < DOUT * (K / 4); i += 256) {
    int c = i / (K / 4);
    int k4 = i % (K / 4);
    float4 w = ((const float4*)W)[i];
    Wt[(k4 * 4 + 0) * DOUT + c] = w.x;
    Wt[(k4 * 4 + 1) * DOUT + c] = w.y;
    Wt[(k4 * 4 + 2) * DOUT + c] = w.z;
    Wt[(k4 * 4 + 3) * DOUT + c] = w.w;
  }

  const int r = threadIdx.x / CG;
  const int c0 = (threadIdx.x % CG) * 4;

  for (int t = blockIdx.x; t < ntiles; t += gridDim.x) {
    const int row0 = t * ROWS;
    __syncthreads();
    for (int i = threadIdx.x; i < ROWS * (K / 4); i += 256) {
      int n = row0 + i / (K / 4);
      float4 v = (n < N) ? ((const float4*)(A + (size_t)n * K))[i % (K / 4)]
                         : make_float4(0.f, 0.f, 0.f, 0.f);
      ((float4*)Al)[i] = v;
    }
    __syncthreads();

    float4 acc0 = make_float4(0.f, 0.f, 0.f, 0.f);
    float4 acc1 = make_float4(0.f, 0.f, 0.f, 0.f);
#pragma unroll 8
    for (int k = 0; k < K; ++k) {
      float a0 = Al[r * K + k];
      float a1 = Al[(r + RH) * K + k];
      float4 w = *(const float4*)&Wt[k * DOUT + c0];
      acc0.x += a0 * w.x; acc0.y += a0 * w.y;
      acc0.z += a0 * w.z; acc0.w += a0 * w.w;
      acc1.x += a1 * w.x; acc1.y += a1 * w.y;
      acc1.z += a1 * w.z; acc1.w += a1 * w.w;
    }

#pragma unroll
    for (int h = 0; h < 2; ++h) {
      int n = row0 + r + h * RH;
      if (n < N) {
        float4 acc = (h == 0) ? acc0 : acc1;
        *(float4*)&out[(size_t)n * DOUT + c0] = acc;
      }
    }
  }
}

// ---------------- fused epilogue: out = mean-gather(Y) + b + A@W.T (+relu+drop)
// out may alias A (A access is tile-local; rows staged to LDS before write).
template <int DOUT, bool RELU, bool DROP>
__global__ __launch_bounds__(256) void sage_epi_kernel(
    const float* A, const float* __restrict__ W,
    const float* __restrict__ bias, const float* __restrict__ Y,
    const int* __restrict__ offs, const int* __restrict__ elist,
    const float* __restrict__ U, float* out, int ntiles) {
  constexpr int CG = DOUT / 4;
  constexpr int RH = 256 / CG;
  constexpr int ROWS = RH * 2;
  __shared__ float Wt[K * DOUT];
  __shared__ float Al[ROWS * K];

  for (int i = threadIdx.x; i < DOUT * (K / 4); i += 256) {
    int c = i / (K / 4);
    int k4 = i % (K / 4);
    float4 w = ((const float4*)W)[i];
    Wt[(k4 * 4 + 0) * DOUT + c] = w.x;
    Wt[(k4 * 4 + 1) * DOUT + c] = w.y;
    Wt[(k4 * 4 + 2) * DOUT + c] = w.z;
    Wt[(k4 * 4 + 3) * DOUT + c] = w.w;
  }

  const int r = threadIdx.x / CG;
  const int cg = threadIdx.x % CG;
  const int c0 = cg * 4;

  for (int t = blockIdx.x; t < ntiles; t += gridDim.x) {
    const int row0 = t * ROWS;
    __syncthreads();
    for (int i = threadIdx.x; i < ROWS * (K / 4); i += 256) {
      int n = row0 + i / (K / 4);
      float4 v = (n < N) ? ((const float4*)(A + (size_t)n * K))[i % (K / 4)]
                         : make_float4(0.f, 0.f, 0.f, 0.f);
      ((float4*)Al)[i] = v;
    }
    __syncthreads();

    float4 acc0 = make_float4(0.f, 0.f, 0.f, 0.f);
    float4 acc1 = make_float4(0.f, 0.f, 0.f, 0.f);
#pragma unroll 8
    for (int k = 0; k < K; ++k) {
      float a0 = Al[r * K + k];
      float a1 = Al[(r + RH) * K + k];
      float4 w = *(const float4*)&Wt[k * DOUT + c0];
      acc0.x += a0 * w.x; acc0.y += a0 * w.y;
      acc0.z += a0 * w.z; acc0.w += a0 * w.w;
      acc1.x += a1 * w.x; acc1.y += a1 * w.y;
      acc1.z += a1 * w.z; acc1.w += a1 * w.w;
    }

#pragma unroll
    for (int h = 0; h < 2; ++h) {
      int n = row0 + r + h * RH;
      if (n < N) {
        float4 acc = (h == 0) ? acc0 : acc1;
        // gather-reduce this node's neighbor segment of Y (coalesced 512B rows)
        const int e0 = offs[n];
        const int e1 = offs[n + 1];
        float4 g = make_float4(0.f, 0.f, 0.f, 0.f);
        for (int e = e0; e < e1; ++e) {
          int s = elist[e];
          float4 yv = ((const float4*)(Y + (size_t)s * DOUT))[cg];
          g.x += yv.x; g.y += yv.y; g.z += yv.z; g.w += yv.w;
        }
        float inv = 1.0f / (float)max(e1 - e0, 1);
        size_t base = (size_t)n * DOUT + c0;
        float4 b = *(const float4*)&bias[c0];
        float4 v;
        v.x = g.x * inv + b.x + acc.x;
        v.y = g.y * inv + b.y + acc.y;
        v.z = g.z * inv + b.z + acc.z;
        v.w = g.w * inv + b.w + acc.w;
        if (RELU) {
          v.x = fmaxf(v.x, 0.f); v.y = fmaxf(v.y, 0.f);
          v.z = fmaxf(v.z, 0.f); v.w = fmaxf(v.w, 0.f);
        }
        if (DROP) {
          const float sc = 1.0f / 0.7f;
          float4 u = *(const float4*)&U[base];
          v.x *= (u.x >= 0.3f) ? sc : 0.f;
          v.y *= (u.y >= 0.3f) ? sc : 0.f;
          v.z *= (u.z >= 0.3f) ? sc : 0.f;
          v.w *= (u.w >= 0.3f) ? sc : 0.f;
        }
        *(float4*)&out[base] = v;
      }
    }
  }
}

extern "C" void kernel_launch(void* const* d_in, const int* in_sizes, int n_in,
                              void* d_out, int out_size, void* d_ws, size_t ws_size,
                              hipStream_t stream) {
  const float* x   = (const float*)d_in[0];
  const float* u1  = (const float*)d_in[1];
  const float* u2  = (const float*)d_in[2];
  const float* wl0 = (const float*)d_in[3];
  const float* bl0 = (const float*)d_in[4];
  const float* wr0 = (const float*)d_in[5];
  const float* wl1 = (const float*)d_in[6];
  const float* bl1 = (const float*)d_in[7];
  const float* wr1 = (const float*)d_in[8];
  const float* wl2 = (const float*)d_in[9];
  const float* bl2 = (const float*)d_in[10];
  const float* wr2 = (const float*)d_in[11];
  const int* edge  = (const int*)d_in[12];
  const int* src = edge;
  const int* dst = edge + E;
  float* out = (float*)d_out;

  float* B0 = (float*)d_ws;                 // h slab, N x 128
  float* B1 = B0 + (size_t)N * 128;         // Y slab, N x 128
  int* deg    = (int*)(B1 + (size_t)N * 128);
  int* offs   = deg + N;                    // N+1
  int* cursor = offs + N + 1;
  int* elist  = cursor + N;                 // E

  // CSR build (deg must start at 0; everything else fully written).
  hipMemsetAsync(deg, 0, (size_t)N * sizeof(int), stream);
  hist_kernel<<<(E + 255) / 256, 256, 0, stream>>>(dst, deg);
  scan_kernel<<<1, 1024, 0, stream>>>(deg, offs, cursor);
  fill_kernel<<<(E + 255) / 256, 256, 0, stream>>>(src, dst, cursor, elist);

  const int GB = 512;
  const int nt128 = (N + 15) / 16;   // ROWS=16 when DOUT=128
  const int nt64  = (N + 31) / 32;   // ROWS=32 when DOUT=64

  // ---- Layer 0 ----
  gemm_wl_kernel<128><<<GB, 256, 0, stream>>>(x, wl0, B1, nt128);              // Y0
  sage_epi_kernel<128, true, true><<<GB, 256, 0, stream>>>(
      x, wr0, bl0, B1, offs, elist, u1, B0, nt128);                            // h0 -> B0

  // ---- Layer 1 ----
  gemm_wl_kernel<128><<<GB, 256, 0, stream>>>(B0, wl1, B1, nt128);             // Y1
  sage_epi_kernel<128, true, true><<<GB, 256, 0, stream>>>(
      B0, wr1, bl1, B1, offs, elist, u2, B0, nt128);                           // h1 -> B0 (in place)

  // ---- Layer 2 (DOUT=64) ----
  gemm_wl_kernel<64><<<GB, 256, 0, stream>>>(B0, wl2, B1, nt64);               // Y2
  sage_epi_kernel<64, false, false><<<GB, 256, 0, stream>>>(
      B0, wr2, bl2, B1, offs, elist, nullptr, out, nt64);                      // out
}

// Round 3
// 521.387 us; speedup vs baseline: 7.2685x; 1.8260x over previous
//
#include <hip/hip_runtime.h>

// GraphSAGE 3-layer forward, MI355X. Round 3:
//  - aggregate-first (matches reference): M = mean_{e:dst=n} h[src_e]
//  - features kept in f16; per layer ONE MFMA GEMM: out = [M|h]@[wl|wr].T + b
//    (K=256, mfma_f32_16x16x32_f16, weights pre-swizzled to fragment order)
//  - dedicated high-occupancy gather kernel (no LDS, unroll-4 edge ILP)
// Round-2 evidence: epi kernel latency-bound (VALUBusy 10.8%, occ 19%),
// fp32 vector GEMMs ~350us combined. MFMA + split gather attacks both.

constexpr int N = 50000;
constexpr int E = 800000;

typedef _Float16 f16x8 __attribute__((ext_vector_type(8)));
typedef _Float16 f16x4 __attribute__((ext_vector_type(4)));
typedef float f32x4 __attribute__((ext_vector_type(4)));

// ---------------- CSR build ----------------

__global__ void hist_kernel(const int* __restrict__ dst, int* __restrict__ deg) {
  int e = blockIdx.x * 256 + threadIdx.x;
  if (e < E) atomicAdd(&deg[dst[e]], 1);
}

__global__ __launch_bounds__(1024) void scan_kernel(
    const int* __restrict__ deg, int* __restrict__ offs, int* __restrict__ cursor) {
  __shared__ int part[1024];
  const int t = threadIdx.x;
  const int chunk = (N + 1023) / 1024;
  const int lo = t * chunk;
  const int hi = min(lo + chunk, N);
  int s = 0;
  for (int i = lo; i < hi; ++i) s += deg[i];
  part[t] = s;
  __syncthreads();
  for (int off = 1; off < 1024; off <<= 1) {
    int v = (t >= off) ? part[t - off] : 0;
    __syncthreads();
    part[t] += v;
    __syncthreads();
  }
  int run = (t == 0) ? 0 : part[t - 1];
  for (int i = lo; i < hi; ++i) {
    offs[i] = run;
    cursor[i] = run;
    run += deg[i];
  }
  if (t == 1023) offs[N] = E;
}

__global__ void fill_kernel(const int* __restrict__ src, const int* __restrict__ dst,
                            int* __restrict__ cursor, int* __restrict__ elist) {
  int e = blockIdx.x * 256 + threadIdx.x;
  if (e < E) {
    int pos = atomicAdd(&cursor[dst[e]], 1);
    elist[pos] = src[e];
  }
}

// ---------------- fp32 -> f16 convert (x) ----------------
__global__ void convert_kernel(const float* __restrict__ in, _Float16* __restrict__ out) {
  int i = blockIdx.x * 256 + threadIdx.x;   // one thread per 8 elems
  if (i < N * 128 / 8) {
    float4 a = ((const float4*)in)[i * 2];
    float4 b = ((const float4*)in)[i * 2 + 1];
    f16x8 v;
    v[0] = (_Float16)a.x; v[1] = (_Float16)a.y; v[2] = (_Float16)a.z; v[3] = (_Float16)a.w;
    v[4] = (_Float16)b.x; v[5] = (_Float16)b.y; v[6] = (_Float16)b.z; v[7] = (_Float16)b.w;
    ((f16x8*)out)[i] = v;
  }
}

// ---------------- weight fragment table build ----------------
// GEMM loads: Wf[((ct*8+kb)*64 + lane)*8 + j] = Wcat[ct*16+(lane&15)][kb*32+(lane>>4)*8+j]
// where Wcat[c][k] = (k<128) ? wl[c][k] : wr[c][k-128].
template <int DOUT>
__global__ void build_wfrag_kernel(const float* __restrict__ wl, const float* __restrict__ wr,
                                   _Float16* __restrict__ wf) {
  int idx = blockIdx.x * 256 + threadIdx.x;
  if (idx >= DOUT * 256) return;
  int j = idx & 7;
  int lane = (idx >> 3) & 63;
  int kb = (idx >> 9) & 7;
  int ct = idx >> 12;
  int c = ct * 16 + (lane & 15);
  int k = kb * 32 + (lane >> 4) * 8 + j;
  float v = (k < 128) ? wl[c * 128 + k] : wr[c * 128 + (k - 128)];
  wf[idx] = (_Float16)v;
}

// ---------------- gather: M[n,:] = mean of H[src,:] over CSR segment ----------------
// Half-wave (32 lanes) per node; lane covers 4 f16 (8B); unroll-4 edge ILP.
__global__ __launch_bounds__(256) void gather_kernel(
    const _Float16* __restrict__ H, const int* __restrict__ offs,
    const int* __restrict__ elist, _Float16* __restrict__ M) {
  int node = blockIdx.x * 8 + (threadIdx.x >> 5);
  if (node >= N) return;
  int l = threadIdx.x & 31;
  const int e0 = offs[node];
  const int e1 = offs[node + 1];
  float a0 = 0.f, a1 = 0.f, a2 = 0.f, a3 = 0.f;
  int e = e0;
  for (; e + 4 <= e1; e += 4) {
    int s0 = elist[e], s1 = elist[e + 1], s2 = elist[e + 2], s3 = elist[e + 3];
    f16x4 v0 = *(const f16x4*)(H + (size_t)s0 * 128 + l * 4);
    f16x4 v1 = *(const f16x4*)(H + (size_t)s1 * 128 + l * 4);
    f16x4 v2 = *(const f16x4*)(H + (size_t)s2 * 128 + l * 4);
    f16x4 v3 = *(const f16x4*)(H + (size_t)s3 * 128 + l * 4);
    a0 += (float)v0[0] + (float)v1[0] + (float)v2[0] + (float)v3[0];
    a1 += (float)v0[1] + (float)v1[1] + (float)v2[1] + (float)v3[1];
    a2 += (float)v0[2] + (float)v1[2] + (float)v2[2] + (float)v3[2];
    a3 += (float)v0[3] + (float)v1[3] + (float)v2[3] + (float)v3[3];
  }
  for (; e < e1; ++e) {
    f16x4 v = *(const f16x4*)(H + (size_t)elist[e] * 128 + l * 4);
    a0 += (float)v[0]; a1 += (float)v[1]; a2 += (float)v[2]; a3 += (float)v[3];
  }
  float inv = 1.0f / (float)max(e1 - e0, 1);
  f16x4 o;
  o[0] = (_Float16)(a0 * inv); o[1] = (_Float16)(a1 * inv);
  o[2] = (_Float16)(a2 * inv); o[3] = (_Float16)(a3 * inv);
  *(f16x4*)(M + (size_t)node * 128 + l * 4) = o;
}

// ---------------- fused MFMA GEMM: out = [M|H] @ Wcat.T + b (+relu+drop) ----------------
// Block = 256 thr = 4 waves; wave handles 32 rows (2 A-frags); block tile 128 rows.
// A-frags straight from global (16B/lane); B-frags from pre-swizzled Wf (contiguous).
template <int DOUT, bool RELU, bool DROP, bool OUTF32>
__global__ __launch_bounds__(256) void mfma_gemm_kernel(
    const _Float16* __restrict__ Mm, const _Float16* __restrict__ Hh,
    const _Float16* __restrict__ Wf, const float* __restrict__ bias,
    const float* __restrict__ U, void* __restrict__ outp) {
  constexpr int CT = DOUT / 16;
  const int lane = threadIdx.x & 63;
  const int w = threadIdx.x >> 6;
  const int n16 = lane & 15;
  const int q = lane >> 4;
  const int rowbase = blockIdx.x * 128 + w * 32;

  f32x4 acc[2][CT];
#pragma unroll
  for (int h = 0; h < 2; ++h)
#pragma unroll
    for (int ct = 0; ct < CT; ++ct) acc[h][ct] = (f32x4){0.f, 0.f, 0.f, 0.f};

  int ar0 = rowbase + n16;
  int ar1 = rowbase + 16 + n16;
  if (ar0 >= N) ar0 = N - 1;   // clamped garbage only feeds discarded rows
  if (ar1 >= N) ar1 = N - 1;
  const _Float16* pM0 = Mm + (size_t)ar0 * 128 + q * 8;
  const _Float16* pM1 = Mm + (size_t)ar1 * 128 + q * 8;
  const _Float16* pH0 = Hh + (size_t)ar0 * 128 + q * 8;
  const _Float16* pH1 = Hh + (size_t)ar1 * 128 + q * 8;

#pragma unroll
  for (int kb = 0; kb < 8; ++kb) {
    const int ko = (kb & 3) * 32;
    f16x8 a0 = *(const f16x8*)((kb < 4 ? pM0 : pH0) + ko);
    f16x8 a1 = *(const f16x8*)((kb < 4 ? pM1 : pH1) + ko);
#pragma unroll
    for (int ct = 0; ct < CT; ++ct) {
      f16x8 b = *(const f16x8*)(Wf + ((size_t)(ct * 8 + kb) * 64 + lane) * 8);
      acc[0][ct] = __builtin_amdgcn_mfma_f32_16x16x32_f16(a0, b, acc[0][ct], 0, 0, 0);
      acc[1][ct] = __builtin_amdgcn_mfma_f32_16x16x32_f16(a1, b, acc[1][ct], 0, 0, 0);
    }
  }

  // epilogue; C/D layout: col = lane&15, row = (lane>>4)*4 + reg
#pragma unroll
  for (int h = 0; h < 2; ++h) {
#pragma unroll
    for (int ct = 0; ct < CT; ++ct) {
      const int col = ct * 16 + n16;
      const float bv = bias[col];
#pragma unroll
      for (int r = 0; r < 4; ++r) {
        int row = rowbase + h * 16 + q * 4 + r;
        if (row < N) {
          float v = acc[h][ct][r] + bv;
          if (RELU) v = fmaxf(v, 0.f);
          if (DROP) {
            float u = U[(size_t)row * 128 + col];
            v *= (u >= 0.3f) ? (1.0f / 0.7f) : 0.0f;
          }
          if (OUTF32) ((float*)outp)[(size_t)row * DOUT + col] = v;
          else ((_Float16*)outp)[(size_t)row * DOUT + col] = (_Float16)v;
        }
      }
    }
  }
}

extern "C" void kernel_launch(void* const* d_in, const int* in_sizes, int n_in,
                              void* d_out, int out_size, void* d_ws, size_t ws_size,
                              hipStream_t stream) {
  const float* x   = (const float*)d_in[0];
  const float* u1  = (const float*)d_in[1];
  const float* u2  = (const float*)d_in[2];
  const float* wl0 = (const float*)d_in[3];
  const float* bl0 = (const float*)d_in[4];
  const float* wr0 = (const float*)d_in[5];
  const float* wl1 = (const float*)d_in[6];
  const float* bl1 = (const float*)d_in[7];
  const float* wr1 = (const float*)d_in[8];
  const float* wl2 = (const float*)d_in[9];
  const float* bl2 = (const float*)d_in[10];
  const float* wr2 = (const float*)d_in[11];
  const int* edge  = (const int*)d_in[12];
  const int* src = edge;
  const int* dst = edge + E;

  // workspace layout (16B-aligned slabs)
  _Float16* HA = (_Float16*)d_ws;                  // N x 128 f16
  _Float16* HB = HA + (size_t)N * 128;             // N x 128 f16
  _Float16* M16 = HB + (size_t)N * 128;            // N x 128 f16
  int* deg    = (int*)(M16 + (size_t)N * 128);
  int* offs   = deg + N;                           // N+1
  int* cursor = offs + N + 1;
  int* elist  = cursor + N;                        // E
  uintptr_t p = (uintptr_t)(elist + E);
  p = (p + 15) & ~(uintptr_t)15;
  _Float16* wf0 = (_Float16*)p;                    // 128*256
  _Float16* wf1 = wf0 + 128 * 256;
  _Float16* wf2 = wf1 + 128 * 256;                 // 64*256

  // CSR build
  hipMemsetAsync(deg, 0, (size_t)N * sizeof(int), stream);
  hist_kernel<<<(E + 255) / 256, 256, 0, stream>>>(dst, deg);
  scan_kernel<<<1, 1024, 0, stream>>>(deg, offs, cursor);
  fill_kernel<<<(E + 255) / 256, 256, 0, stream>>>(src, dst, cursor, elist);

  // converts
  convert_kernel<<<(N * 128 / 8 + 255) / 256, 256, 0, stream>>>(x, HA);
  build_wfrag_kernel<128><<<128, 256, 0, stream>>>(wl0, wr0, wf0);
  build_wfrag_kernel<128><<<128, 256, 0, stream>>>(wl1, wr1, wf1);
  build_wfrag_kernel<64><<<64, 256, 0, stream>>>(wl2, wr2, wf2);

  const int GG = (N + 7) / 8;        // gather grid
  const int GM = (N + 127) / 128;    // gemm grid

  // ---- Layer 0 ----
  gather_kernel<<<GG, 256, 0, stream>>>(HA, offs, elist, M16);
  mfma_gemm_kernel<128, true, true, false><<<GM, 256, 0, stream>>>(
      M16, HA, wf0, bl0, u1, HB);
  // ---- Layer 1 ----
  gather_kernel<<<GG, 256, 0, stream>>>(HB, offs, elist, M16);
  mfma_gemm_kernel<128, true, true, false><<<GM, 256, 0, stream>>>(
      M16, HB, wf1, bl1, u2, HA);
  // ---- Layer 2 ----
  gather_kernel<<<GG, 256, 0, stream>>>(HA, offs, elist, M16);
  mfma_gemm_kernel<64, false, false, true><<<GM, 256, 0, stream>>>(
      M16, HA, wf2, bl2, nullptr, d_out);
}

// Round 4
// 421.872 us; speedup vs baseline: 8.9830x; 1.2359x over previous
//
#include <hip/hip_runtime.h>

// GraphSAGE 3-layer forward, MI355X. Round 4:
//   Round-3 profile: single-block scan_kernel = 111 us (21% of total,
//   occupancy 0.14% — one CU). Replace with 3-launch multi-block scan
//   (block sums -> scan sums -> local scan + offset). Everything else
//   unchanged from round 3 (f16 features, fused MFMA GEMM, CSR gather).

constexpr int N = 50000;
constexpr int E = 800000;
constexpr int NB = (N + 255) / 256;   // 196 scan blocks

typedef _Float16 f16x8 __attribute__((ext_vector_type(8)));
typedef _Float16 f16x4 __attribute__((ext_vector_type(4)));
typedef float f32x4 __attribute__((ext_vector_type(4)));

// ---------------- CSR build ----------------

__global__ void hist_kernel(const int* __restrict__ dst, int* __restrict__ deg) {
  int e = blockIdx.x * 256 + threadIdx.x;
  if (e < E) atomicAdd(&deg[dst[e]], 1);
}

// (a) per-block sums of deg
__global__ __launch_bounds__(256) void scan_partial_kernel(
    const int* __restrict__ deg, int* __restrict__ blocksum) {
  __shared__ int s[256];
  const int t = threadIdx.x;
  const int i = blockIdx.x * 256 + t;
  s[t] = (i < N) ? deg[i] : 0;
  __syncthreads();
  for (int off = 128; off > 0; off >>= 1) {
    if (t < off) s[t] += s[t + off];
    __syncthreads();
  }
  if (t == 0) blocksum[blockIdx.x] = s[0];
}

// (b) exclusive scan of blocksum[NB] (single tiny block, all in LDS)
__global__ __launch_bounds__(256) void scan_sums_kernel(
    const int* __restrict__ blocksum, int* __restrict__ blockoff) {
  __shared__ int s[256];
  const int t = threadIdx.x;
  int v = (t < NB) ? blocksum[t] : 0;
  s[t] = v;
  __syncthreads();
  for (int off = 1; off < 256; off <<= 1) {
    int u = (t >= off) ? s[t - off] : 0;
    __syncthreads();
    s[t] += u;
    __syncthreads();
  }
  if (t < NB) blockoff[t] = s[t] - v;   // exclusive
}

// (c) per-block exclusive scan + block offset -> offs, cursor
__global__ __launch_bounds__(256) void scan_final_kernel(
    const int* __restrict__ deg, const int* __restrict__ blockoff,
    int* __restrict__ offs, int* __restrict__ cursor) {
  __shared__ int s[256];
  const int t = threadIdx.x;
  const int i = blockIdx.x * 256 + t;
  int v = (i < N) ? deg[i] : 0;
  s[t] = v;
  __syncthreads();
  for (int off = 1; off < 256; off <<= 1) {
    int u = (t >= off) ? s[t - off] : 0;
    __syncthreads();
    s[t] += u;
    __syncthreads();
  }
  if (i < N) {
    int o = blockoff[blockIdx.x] + s[t] - v;
    offs[i] = o;
    cursor[i] = o;
  }
  if (i == 0) offs[N] = E;
}

__global__ void fill_kernel(const int* __restrict__ src, const int* __restrict__ dst,
                            int* __restrict__ cursor, int* __restrict__ elist) {
  int e = blockIdx.x * 256 + threadIdx.x;
  if (e < E) {
    int pos = atomicAdd(&cursor[dst[e]], 1);
    elist[pos] = src[e];
  }
}

// ---------------- fp32 -> f16 convert (x) ----------------
__global__ void convert_kernel(const float* __restrict__ in, _Float16* __restrict__ out) {
  int i = blockIdx.x * 256 + threadIdx.x;   // one thread per 8 elems
  if (i < N * 128 / 8) {
    float4 a = ((const float4*)in)[i * 2];
    float4 b = ((const float4*)in)[i * 2 + 1];
    f16x8 v;
    v[0] = (_Float16)a.x; v[1] = (_Float16)a.y; v[2] = (_Float16)a.z; v[3] = (_Float16)a.w;
    v[4] = (_Float16)b.x; v[5] = (_Float16)b.y; v[6] = (_Float16)b.z; v[7] = (_Float16)b.w;
    ((f16x8*)out)[i] = v;
  }
}

// ---------------- weight fragment table build ----------------
// GEMM loads: Wf[((ct*8+kb)*64 + lane)*8 + j] = Wcat[ct*16+(lane&15)][kb*32+(lane>>4)*8+j]
// where Wcat[c][k] = (k<128) ? wl[c][k] : wr[c][k-128].
template <int DOUT>
__global__ void build_wfrag_kernel(const float* __restrict__ wl, const float* __restrict__ wr,
                                   _Float16* __restrict__ wf) {
  int idx = blockIdx.x * 256 + threadIdx.x;
  if (idx >= DOUT * 256) return;
  int j = idx & 7;
  int lane = (idx >> 3) & 63;
  int kb = (idx >> 9) & 7;
  int ct = idx >> 12;
  int c = ct * 16 + (lane & 15);
  int k = kb * 32 + (lane >> 4) * 8 + j;
  float v = (k < 128) ? wl[c * 128 + k] : wr[c * 128 + (k - 128)];
  wf[idx] = (_Float16)v;
}

// ---------------- gather: M[n,:] = mean of H[src,:] over CSR segment ----------------
// Half-wave (32 lanes) per node; lane covers 4 f16 (8B); unroll-4 edge ILP.
__global__ __launch_bounds__(256) void gather_kernel(
    const _Float16* __restrict__ H, const int* __restrict__ offs,
    const int* __restrict__ elist, _Float16* __restrict__ M) {
  int node = blockIdx.x * 8 + (threadIdx.x >> 5);
  if (node >= N) return;
  int l = threadIdx.x & 31;
  const int e0 = offs[node];
  const int e1 = offs[node + 1];
  float a0 = 0.f, a1 = 0.f, a2 = 0.f, a3 = 0.f;
  int e = e0;
  for (; e + 4 <= e1; e += 4) {
    int s0 = elist[e], s1 = elist[e + 1], s2 = elist[e + 2], s3 = elist[e + 3];
    f16x4 v0 = *(const f16x4*)(H + (size_t)s0 * 128 + l * 4);
    f16x4 v1 = *(const f16x4*)(H + (size_t)s1 * 128 + l * 4);
    f16x4 v2 = *(const f16x4*)(H + (size_t)s2 * 128 + l * 4);
    f16x4 v3 = *(const f16x4*)(H + (size_t)s3 * 128 + l * 4);
    a0 += (float)v0[0] + (float)v1[0] + (float)v2[0] + (float)v3[0];
    a1 += (float)v0[1] + (float)v1[1] + (float)v2[1] + (float)v3[1];
    a2 += (float)v0[2] + (float)v1[2] + (float)v2[2] + (float)v3[2];
    a3 += (float)v0[3] + (float)v1[3] + (float)v2[3] + (float)v3[3];
  }
  for (; e < e1; ++e) {
    f16x4 v = *(const f16x4*)(H + (size_t)elist[e] * 128 + l * 4);
    a0 += (float)v[0]; a1 += (float)v[1]; a2 += (float)v[2]; a3 += (float)v[3];
  }
  float inv = 1.0f / (float)max(e1 - e0, 1);
  f16x4 o;
  o[0] = (_Float16)(a0 * inv); o[1] = (_Float16)(a1 * inv);
  o[2] = (_Float16)(a2 * inv); o[3] = (_Float16)(a3 * inv);
  *(f16x4*)(M + (size_t)node * 128 + l * 4) = o;
}

// ---------------- fused MFMA GEMM: out = [M|H] @ Wcat.T + b (+relu+drop) ----------------
// Block = 256 thr = 4 waves; wave handles 32 rows (2 A-frags); block tile 128 rows.
// A-frags straight from global (16B/lane); B-frags from pre-swizzled Wf (contiguous).
template <int DOUT, bool RELU, bool DROP, bool OUTF32>
__global__ __launch_bounds__(256) void mfma_gemm_kernel(
    const _Float16* __restrict__ Mm, const _Float16* __restrict__ Hh,
    const _Float16* __restrict__ Wf, const float* __restrict__ bias,
    const float* __restrict__ U, void* __restrict__ outp) {
  constexpr int CT = DOUT / 16;
  const int lane = threadIdx.x & 63;
  const int w = threadIdx.x >> 6;
  const int n16 = lane & 15;
  const int q = lane >> 4;
  const int rowbase = blockIdx.x * 128 + w * 32;

  f32x4 acc[2][CT];
#pragma unroll
  for (int h = 0; h < 2; ++h)
#pragma unroll
    for (int ct = 0; ct < CT; ++ct) acc[h][ct] = (f32x4){0.f, 0.f, 0.f, 0.f};

  int ar0 = rowbase + n16;
  int ar1 = rowbase + 16 + n16;
  if (ar0 >= N) ar0 = N - 1;   // clamped garbage only feeds discarded rows
  if (ar1 >= N) ar1 = N - 1;
  const _Float16* pM0 = Mm + (size_t)ar0 * 128 + q * 8;
  const _Float16* pM1 = Mm + (size_t)ar1 * 128 + q * 8;
  const _Float16* pH0 = Hh + (size_t)ar0 * 128 + q * 8;
  const _Float16* pH1 = Hh + (size_t)ar1 * 128 + q * 8;

#pragma unroll
  for (int kb = 0; kb < 8; ++kb) {
    const int ko = (kb & 3) * 32;
    f16x8 a0 = *(const f16x8*)((kb < 4 ? pM0 : pH0) + ko);
    f16x8 a1 = *(const f16x8*)((kb < 4 ? pM1 : pH1) + ko);
#pragma unroll
    for (int ct = 0; ct < CT; ++ct) {
      f16x8 b = *(const f16x8*)(Wf + ((size_t)(ct * 8 + kb) * 64 + lane) * 8);
      acc[0][ct] = __builtin_amdgcn_mfma_f32_16x16x32_f16(a0, b, acc[0][ct], 0, 0, 0);
      acc[1][ct] = __builtin_amdgcn_mfma_f32_16x16x32_f16(a1, b, acc[1][ct], 0, 0, 0);
    }
  }

  // epilogue; C/D layout: col = lane&15, row = (lane>>4)*4 + reg
#pragma unroll
  for (int h = 0; h < 2; ++h) {
#pragma unroll
    for (int ct = 0; ct < CT; ++ct) {
      const int col = ct * 16 + n16;
      const float bv = bias[col];
#pragma unroll
      for (int r = 0; r < 4; ++r) {
        int row = rowbase + h * 16 + q * 4 + r;
        if (row < N) {
          float v = acc[h][ct][r] + bv;
          if (RELU) v = fmaxf(v, 0.f);
          if (DROP) {
            float u = U[(size_t)row * 128 + col];
            v *= (u >= 0.3f) ? (1.0f / 0.7f) : 0.0f;
          }
          if (OUTF32) ((float*)outp)[(size_t)row * DOUT + col] = v;
          else ((_Float16*)outp)[(size_t)row * DOUT + col] = (_Float16)v;
        }
      }
    }
  }
}

extern "C" void kernel_launch(void* const* d_in, const int* in_sizes, int n_in,
                              void* d_out, int out_size, void* d_ws, size_t ws_size,
                              hipStream_t stream) {
  const float* x   = (const float*)d_in[0];
  const float* u1  = (const float*)d_in[1];
  const float* u2  = (const float*)d_in[2];
  const float* wl0 = (const float*)d_in[3];
  const float* bl0 = (const float*)d_in[4];
  const float* wr0 = (const float*)d_in[5];
  const float* wl1 = (const float*)d_in[6];
  const float* bl1 = (const float*)d_in[7];
  const float* wr1 = (const float*)d_in[8];
  const float* wl2 = (const float*)d_in[9];
  const float* bl2 = (const float*)d_in[10];
  const float* wr2 = (const float*)d_in[11];
  const int* edge  = (const int*)d_in[12];
  const int* src = edge;
  const int* dst = edge + E;

  // workspace layout (16B-aligned slabs)
  _Float16* HA = (_Float16*)d_ws;                  // N x 128 f16
  _Float16* HB = HA + (size_t)N * 128;             // N x 128 f16
  _Float16* M16 = HB + (size_t)N * 128;            // N x 128 f16
  int* deg    = (int*)(M16 + (size_t)N * 128);
  int* offs   = deg + N;                           // N+1
  int* cursor = offs + N + 1;
  int* elist  = cursor + N;                        // E
  int* blocksum = elist + E;                       // NB
  int* blockoff = blocksum + NB;                   // NB
  uintptr_t p = (uintptr_t)(blockoff + NB);
  p = (p + 15) & ~(uintptr_t)15;
  _Float16* wf0 = (_Float16*)p;                    // 128*256
  _Float16* wf1 = wf0 + 128 * 256;
  _Float16* wf2 = wf1 + 128 * 256;                 // 64*256

  // CSR build (multi-block scan: round-3's 1-block scan was 111 us)
  hipMemsetAsync(deg, 0, (size_t)N * sizeof(int), stream);
  hist_kernel<<<(E + 255) / 256, 256, 0, stream>>>(dst, deg);
  scan_partial_kernel<<<NB, 256, 0, stream>>>(deg, blocksum);
  scan_sums_kernel<<<1, 256, 0, stream>>>(blocksum, blockoff);
  scan_final_kernel<<<NB, 256, 0, stream>>>(deg, blockoff, offs, cursor);
  fill_kernel<<<(E + 255) / 256, 256, 0, stream>>>(src, dst, cursor, elist);

  // converts
  convert_kernel<<<(N * 128 / 8 + 255) / 256, 256, 0, stream>>>(x, HA);
  build_wfrag_kernel<128><<<128, 256, 0, stream>>>(wl0, wr0, wf0);
  build_wfrag_kernel<128><<<128, 256, 0, stream>>>(wl1, wr1, wf1);
  build_wfrag_kernel<64><<<64, 256, 0, stream>>>(wl2, wr2, wf2);

  const int GG = (N + 7) / 8;        // gather grid
  const int GM = (N + 127) / 128;    // gemm grid

  // ---- Layer 0 ----
  gather_kernel<<<GG, 256, 0, stream>>>(HA, offs, elist, M16);
  mfma_gemm_kernel<128, true, true, false><<<GM, 256, 0, stream>>>(
      M16, HA, wf0, bl0, u1, HB);
  // ---- Layer 1 ----
  gather_kernel<<<GG, 256, 0, stream>>>(HB, offs, elist, M16);
  mfma_gemm_kernel<128, true, true, false><<<GM, 256, 0, stream>>>(
      M16, HB, wf1, bl1, u2, HA);
  // ---- Layer 2 ----
  gather_kernel<<<GG, 256, 0, stream>>>(HA, offs, elist, M16);
  mfma_gemm_kernel<64, false, false, true><<<GM, 256, 0, stream>>>(
      M16, HA, wf2, bl2, nullptr, d_out);
}

// Round 5
// 383.458 us; speedup vs baseline: 9.8829x; 1.1002x over previous
//
#include <hip/hip_runtime.h>

// GraphSAGE 3-layer forward, MI355X. Round 5:
//   Round-4 profile: mfma_gemm<128> 54us x2, MfmaUtil 2.1%, occupancy 12.8%
//   (391 blocks x 4 waves = 1564 waves -> ~1 wave/SIMD, latency-bound).
//   Fix: wave tile 32x128 -> 32x32 (CT=2); block = 32 rows x 128 cols so the
//   4 waves share A rows via L1; grid 391 -> 1563 blocks (6252 waves).
//   CSR build / gather / converts unchanged from round 4.

constexpr int N = 50000;
constexpr int E = 800000;
constexpr int NB = (N + 255) / 256;   // 196 scan blocks

typedef _Float16 f16x8 __attribute__((ext_vector_type(8)));
typedef _Float16 f16x4 __attribute__((ext_vector_type(4)));
typedef float f32x4 __attribute__((ext_vector_type(4)));

// ---------------- CSR build ----------------

__global__ void hist_kernel(const int* __restrict__ dst, int* __restrict__ deg) {
  int e = blockIdx.x * 256 + threadIdx.x;
  if (e < E) atomicAdd(&deg[dst[e]], 1);
}

__global__ __launch_bounds__(256) void scan_partial_kernel(
    const int* __restrict__ deg, int* __restrict__ blocksum) {
  __shared__ int s[256];
  const int t = threadIdx.x;
  const int i = blockIdx.x * 256 + t;
  s[t] = (i < N) ? deg[i] : 0;
  __syncthreads();
  for (int off = 128; off > 0; off >>= 1) {
    if (t < off) s[t] += s[t + off];
    __syncthreads();
  }
  if (t == 0) blocksum[blockIdx.x] = s[0];
}

__global__ __launch_bounds__(256) void scan_sums_kernel(
    const int* __restrict__ blocksum, int* __restrict__ blockoff) {
  __shared__ int s[256];
  const int t = threadIdx.x;
  int v = (t < NB) ? blocksum[t] : 0;
  s[t] = v;
  __syncthreads();
  for (int off = 1; off < 256; off <<= 1) {
    int u = (t >= off) ? s[t - off] : 0;
    __syncthreads();
    s[t] += u;
    __syncthreads();
  }
  if (t < NB) blockoff[t] = s[t] - v;   // exclusive
}

__global__ __launch_bounds__(256) void scan_final_kernel(
    const int* __restrict__ deg, const int* __restrict__ blockoff,
    int* __restrict__ offs, int* __restrict__ cursor) {
  __shared__ int s[256];
  const int t = threadIdx.x;
  const int i = blockIdx.x * 256 + t;
  int v = (i < N) ? deg[i] : 0;
  s[t] = v;
  __syncthreads();
  for (int off = 1; off < 256; off <<= 1) {
    int u = (t >= off) ? s[t - off] : 0;
    __syncthreads();
    s[t] += u;
    __syncthreads();
  }
  if (i < N) {
    int o = blockoff[blockIdx.x] + s[t] - v;
    offs[i] = o;
    cursor[i] = o;
  }
  if (i == 0) offs[N] = E;
}

__global__ void fill_kernel(const int* __restrict__ src, const int* __restrict__ dst,
                            int* __restrict__ cursor, int* __restrict__ elist) {
  int e = blockIdx.x * 256 + threadIdx.x;
  if (e < E) {
    int pos = atomicAdd(&cursor[dst[e]], 1);
    elist[pos] = src[e];
  }
}

// ---------------- fp32 -> f16 convert (x) ----------------
__global__ void convert_kernel(const float* __restrict__ in, _Float16* __restrict__ out) {
  int i = blockIdx.x * 256 + threadIdx.x;   // one thread per 8 elems
  if (i < N * 128 / 8) {
    float4 a = ((const float4*)in)[i * 2];
    float4 b = ((const float4*)in)[i * 2 + 1];
    f16x8 v;
    v[0] = (_Float16)a.x; v[1] = (_Float16)a.y; v[2] = (_Float16)a.z; v[3] = (_Float16)a.w;
    v[4] = (_Float16)b.x; v[5] = (_Float16)b.y; v[6] = (_Float16)b.z; v[7] = (_Float16)b.w;
    ((f16x8*)out)[i] = v;
  }
}

// ---------------- weight fragment table build ----------------
// GEMM loads: Wf[((ct*8+kb)*64 + lane)*8 + j] = Wcat[ct*16+(lane&15)][kb*32+(lane>>4)*8+j]
// where Wcat[c][k] = (k<128) ? wl[c][k] : wr[c][k-128].
template <int DOUT>
__global__ void build_wfrag_kernel(const float* __restrict__ wl, const float* __restrict__ wr,
                                   _Float16* __restrict__ wf) {
  int idx = blockIdx.x * 256 + threadIdx.x;
  if (idx >= DOUT * 256) return;
  int j = idx & 7;
  int lane = (idx >> 3) & 63;
  int kb = (idx >> 9) & 7;
  int ct = idx >> 12;
  int c = ct * 16 + (lane & 15);
  int k = kb * 32 + (lane >> 4) * 8 + j;
  float v = (k < 128) ? wl[c * 128 + k] : wr[c * 128 + (k - 128)];
  wf[idx] = (_Float16)v;
}

// ---------------- gather: M[n,:] = mean of H[src,:] over CSR segment ----------------
__global__ __launch_bounds__(256) void gather_kernel(
    const _Float16* __restrict__ H, const int* __restrict__ offs,
    const int* __restrict__ elist, _Float16* __restrict__ M) {
  int node = blockIdx.x * 8 + (threadIdx.x >> 5);
  if (node >= N) return;
  int l = threadIdx.x & 31;
  const int e0 = offs[node];
  const int e1 = offs[node + 1];
  float a0 = 0.f, a1 = 0.f, a2 = 0.f, a3 = 0.f;
  int e = e0;
  for (; e + 4 <= e1; e += 4) {
    int s0 = elist[e], s1 = elist[e + 1], s2 = elist[e + 2], s3 = elist[e + 3];
    f16x4 v0 = *(const f16x4*)(H + (size_t)s0 * 128 + l * 4);
    f16x4 v1 = *(const f16x4*)(H + (size_t)s1 * 128 + l * 4);
    f16x4 v2 = *(const f16x4*)(H + (size_t)s2 * 128 + l * 4);
    f16x4 v3 = *(const f16x4*)(H + (size_t)s3 * 128 + l * 4);
    a0 += (float)v0[0] + (float)v1[0] + (float)v2[0] + (float)v3[0];
    a1 += (float)v0[1] + (float)v1[1] + (float)v2[1] + (float)v3[1];
    a2 += (float)v0[2] + (float)v1[2] + (float)v2[2] + (float)v3[2];
    a3 += (float)v0[3] + (float)v1[3] + (float)v2[3] + (float)v3[3];
  }
  for (; e < e1; ++e) {
    f16x4 v = *(const f16x4*)(H + (size_t)elist[e] * 128 + l * 4);
    a0 += (float)v[0]; a1 += (float)v[1]; a2 += (float)v[2]; a3 += (float)v[3];
  }
  float inv = 1.0f / (float)max(e1 - e0, 1);
  f16x4 o;
  o[0] = (_Float16)(a0 * inv); o[1] = (_Float16)(a1 * inv);
  o[2] = (_Float16)(a2 * inv); o[3] = (_Float16)(a3 * inv);
  *(f16x4*)(M + (size_t)node * 128 + l * 4) = o;
}

// ---------------- fused MFMA GEMM: out = [M|H] @ Wcat.T + b (+relu+drop) ----------------
// Wave tile: 32 rows x 32 cols (2 A-frags x 2 col-tiles). NCG = DOUT/32 col-groups.
// Block (4 waves): (4/NCG)*32 rows x DOUT cols; waves sharing rows hit A in L1.
template <int DOUT, bool RELU, bool DROP, bool OUTF32>
__global__ __launch_bounds__(256, 4) void mfma_gemm_kernel(
    const _Float16* __restrict__ Mm, const _Float16* __restrict__ Hh,
    const _Float16* __restrict__ Wf, const float* __restrict__ bias,
    const float* __restrict__ U, void* __restrict__ outp) {
  constexpr int NCG = DOUT / 32;            // col-groups per block (4 or 2)
  constexpr int RPB = 32 * (4 / NCG);       // rows per block (32 or 64)
  const int lane = threadIdx.x & 63;
  const int w = threadIdx.x >> 6;
  const int colgrp = w % NCG;
  const int rowsel = w / NCG;
  const int n16 = lane & 15;
  const int q = lane >> 4;
  const int rowbase = blockIdx.x * RPB + rowsel * 32;
  const int colbase = colgrp * 32;

  f32x4 acc[2][2];
#pragma unroll
  for (int h = 0; h < 2; ++h)
#pragma unroll
    for (int ct = 0; ct < 2; ++ct) acc[h][ct] = (f32x4){0.f, 0.f, 0.f, 0.f};

  int ar0 = rowbase + n16;
  int ar1 = rowbase + 16 + n16;
  if (ar0 >= N) ar0 = N - 1;   // clamped garbage only feeds discarded rows
  if (ar1 >= N) ar1 = N - 1;
  const _Float16* pM0 = Mm + (size_t)ar0 * 128 + q * 8;
  const _Float16* pM1 = Mm + (size_t)ar1 * 128 + q * 8;
  const _Float16* pH0 = Hh + (size_t)ar0 * 128 + q * 8;
  const _Float16* pH1 = Hh + (size_t)ar1 * 128 + q * 8;

#pragma unroll
  for (int kb = 0; kb < 8; ++kb) {
    const int ko = (kb & 3) * 32;
    f16x8 a0 = *(const f16x8*)((kb < 4 ? pM0 : pH0) + ko);
    f16x8 a1 = *(const f16x8*)((kb < 4 ? pM1 : pH1) + ko);
#pragma unroll
    for (int ct = 0; ct < 2; ++ct) {
      const int ctg = colgrp * 2 + ct;
      f16x8 b = *(const f16x8*)(Wf + ((size_t)(ctg * 8 + kb) * 64 + lane) * 8);
      acc[0][ct] = __builtin_amdgcn_mfma_f32_16x16x32_f16(a0, b, acc[0][ct], 0, 0, 0);
      acc[1][ct] = __builtin_amdgcn_mfma_f32_16x16x32_f16(a1, b, acc[1][ct], 0, 0, 0);
    }
  }

  // epilogue; C/D layout: col = lane&15, row = (lane>>4)*4 + reg
#pragma unroll
  for (int h = 0; h < 2; ++h) {
#pragma unroll
    for (int ct = 0; ct < 2; ++ct) {
      const int col = colbase + ct * 16 + n16;
      const float bv = bias[col];
#pragma unroll
      for (int r = 0; r < 4; ++r) {
        int row = rowbase + h * 16 + q * 4 + r;
        if (row < N) {
          float v = acc[h][ct][r] + bv;
          if (RELU) v = fmaxf(v, 0.f);
          if (DROP) {
            float u = U[(size_t)row * 128 + col];
            v *= (u >= 0.3f) ? (1.0f / 0.7f) : 0.0f;
          }
          if (OUTF32) ((float*)outp)[(size_t)row * DOUT + col] = v;
          else ((_Float16*)outp)[(size_t)row * DOUT + col] = (_Float16)v;
        }
      }
    }
  }
}

extern "C" void kernel_launch(void* const* d_in, const int* in_sizes, int n_in,
                              void* d_out, int out_size, void* d_ws, size_t ws_size,
                              hipStream_t stream) {
  const float* x   = (const float*)d_in[0];
  const float* u1  = (const float*)d_in[1];
  const float* u2  = (const float*)d_in[2];
  const float* wl0 = (const float*)d_in[3];
  const float* bl0 = (const float*)d_in[4];
  const float* wr0 = (const float*)d_in[5];
  const float* wl1 = (const float*)d_in[6];
  const float* bl1 = (const float*)d_in[7];
  const float* wr1 = (const float*)d_in[8];
  const float* wl2 = (const float*)d_in[9];
  const float* bl2 = (const float*)d_in[10];
  const float* wr2 = (const float*)d_in[11];
  const int* edge  = (const int*)d_in[12];
  const int* src = edge;
  const int* dst = edge + E;

  // workspace layout (16B-aligned slabs)
  _Float16* HA = (_Float16*)d_ws;                  // N x 128 f16
  _Float16* HB = HA + (size_t)N * 128;             // N x 128 f16
  _Float16* M16 = HB + (size_t)N * 128;            // N x 128 f16
  int* deg    = (int*)(M16 + (size_t)N * 128);
  int* offs   = deg + N;                           // N+1
  int* cursor = offs + N + 1;
  int* elist  = cursor + N;                        // E
  int* blocksum = elist + E;                       // NB
  int* blockoff = blocksum + NB;                   // NB
  uintptr_t p = (uintptr_t)(blockoff + NB);
  p = (p + 15) & ~(uintptr_t)15;
  _Float16* wf0 = (_Float16*)p;                    // 128*256
  _Float16* wf1 = wf0 + 128 * 256;
  _Float16* wf2 = wf1 + 128 * 256;                 // 64*256

  // CSR build
  hipMemsetAsync(deg, 0, (size_t)N * sizeof(int), stream);
  hist_kernel<<<(E + 255) / 256, 256, 0, stream>>>(dst, deg);
  scan_partial_kernel<<<NB, 256, 0, stream>>>(deg, blocksum);
  scan_sums_kernel<<<1, 256, 0, stream>>>(blocksum, blockoff);
  scan_final_kernel<<<NB, 256, 0, stream>>>(deg, blockoff, offs, cursor);
  fill_kernel<<<(E + 255) / 256, 256, 0, stream>>>(src, dst, cursor, elist);

  // converts
  convert_kernel<<<(N * 128 / 8 + 255) / 256, 256, 0, stream>>>(x, HA);
  build_wfrag_kernel<128><<<128, 256, 0, stream>>>(wl0, wr0, wf0);
  build_wfrag_kernel<128><<<128, 256, 0, stream>>>(wl1, wr1, wf1);
  build_wfrag_kernel<64><<<64, 256, 0, stream>>>(wl2, wr2, wf2);

  const int GG = (N + 7) / 8;          // gather grid
  const int GM128 = (N + 31) / 32;     // 1563 blocks (32 rows/block)
  const int GM64  = (N + 63) / 64;     // 782 blocks (64 rows/block)

  // ---- Layer 0 ----
  gather_kernel<<<GG, 256, 0, stream>>>(HA, offs, elist, M16);
  mfma_gemm_kernel<128, true, true, false><<<GM128, 256, 0, stream>>>(
      M16, HA, wf0, bl0, u1, HB);
  // ---- Layer 1 ----
  gather_kernel<<<GG, 256, 0, stream>>>(HB, offs, elist, M16);
  mfma_gemm_kernel<128, true, true, false><<<GM128, 256, 0, stream>>>(
      M16, HB, wf1, bl1, u2, HA);
  // ---- Layer 2 ----
  gather_kernel<<<GG, 256, 0, stream>>>(HA, offs, elist, M16);
  mfma_gemm_kernel<64, false, false, true><<<GM64, 256, 0, stream>>>(
      M16, HA, wf2, bl2, nullptr, d_out);
}

// Round 6
// 365.010 us; speedup vs baseline: 10.3824x; 1.0505x over previous
//
#include <hip/hip_runtime.h>

// GraphSAGE 3-layer forward, MI355X. Round 6:
//   R5 profile: fill_kernel 52us, WRITE_SIZE 52MB for 3.2MB logical (16x
//   cross-XCD line-RMW amplification on random 4B scatter). Replace with
//   2-phase bucket sort (LDS counting sort -> grouped runs -> per-bucket
//   placement in a 16KB L2-local window). Also: layer-2 transform-first
//   (gather 64-wide Y2, half the bytes) and gather unroll 4->8.

constexpr int N = 50000;
constexpr int E = 800000;
constexpr int NB = (N + 255) / 256;       // 196 scan blocks
constexpr int NBUCKB = (N + 255) / 256;   // 196 dst-buckets (256 nodes each)
constexpr int CE = 4096;                  // edges per bucket_scatter block
constexpr int NEB = (E + CE - 1) / CE;    // 196
static_assert(N <= 65536, "u16 packing");

typedef _Float16 f16x8 __attribute__((ext_vector_type(8)));
typedef _Float16 f16x4 __attribute__((ext_vector_type(4)));
typedef float f32x4 __attribute__((ext_vector_type(4)));

// ---------------- degree + offsets ----------------

__global__ void hist_kernel(const int* __restrict__ dst, int* __restrict__ deg) {
  int e = blockIdx.x * 256 + threadIdx.x;
  if (e < E) atomicAdd(&deg[dst[e]], 1);
}

__global__ __launch_bounds__(256) void scan_partial_kernel(
    const int* __restrict__ deg, int* __restrict__ blocksum) {
  __shared__ int s[256];
  const int t = threadIdx.x;
  const int i = blockIdx.x * 256 + t;
  s[t] = (i < N) ? deg[i] : 0;
  __syncthreads();
  for (int off = 128; off > 0; off >>= 1) {
    if (t < off) s[t] += s[t + off];
    __syncthreads();
  }
  if (t == 0) blocksum[blockIdx.x] = s[0];
}

__global__ __launch_bounds__(256) void scan_sums_kernel(
    const int* __restrict__ blocksum, int* __restrict__ blockoff) {
  __shared__ int s[256];
  const int t = threadIdx.x;
  int v = (t < NB) ? blocksum[t] : 0;
  s[t] = v;
  __syncthreads();
  for (int off = 1; off < 256; off <<= 1) {
    int u = (t >= off) ? s[t - off] : 0;
    __syncthreads();
    s[t] += u;
    __syncthreads();
  }
  if (t < NB) blockoff[t] = s[t] - v;   // exclusive
}

__global__ __launch_bounds__(256) void scan_final_kernel(
    const int* __restrict__ deg, const int* __restrict__ blockoff,
    int* __restrict__ offs) {
  __shared__ int s[256];
  const int t = threadIdx.x;
  const int i = blockIdx.x * 256 + t;
  int v = (i < N) ? deg[i] : 0;
  s[t] = v;
  __syncthreads();
  for (int off = 1; off < 256; off <<= 1) {
    int u = (t >= off) ? s[t - off] : 0;
    __syncthreads();
    s[t] += u;
    __syncthreads();
  }
  if (i < N) offs[i] = blockoff[blockIdx.x] + s[t] - v;
  if (i == 0) offs[N] = E;
}

// ---------------- 2-phase bucket sort (replaces fill_kernel) ----------------

__global__ __launch_bounds__(256) void bucket_cursor_init(
    const int* __restrict__ offs, int* __restrict__ bcur) {
  int b = blockIdx.x * 256 + threadIdx.x;
  if (b < NBUCKB) bcur[b] = offs[min(b * 256, N)];
}

// Phase A: LDS counting sort of a 4096-edge chunk by dst>>8; write grouped
// runs of packed (dst<<16|src) into bucket regions of T (near-coalesced).
__global__ __launch_bounds__(256) void bucket_scatter_kernel(
    const int* __restrict__ src, const int* __restrict__ dst,
    int* __restrict__ bcur, unsigned* __restrict__ T) {
  __shared__ unsigned sorted[CE];
  __shared__ int hist[256], scan[256], excl[256], lcur[256], gbase[256];
  const int t = threadIdx.x;
  const int e0 = blockIdx.x * CE;
  const int nval = min(CE, E - e0);
  hist[t] = 0;
  __syncthreads();
  for (int i = t; i < nval; i += 256) atomicAdd(&hist[dst[e0 + i] >> 8], 1);
  __syncthreads();
  const int h = hist[t];
  scan[t] = h;
  __syncthreads();
  for (int off = 1; off < 256; off <<= 1) {
    int u = (t >= off) ? scan[t - off] : 0;
    __syncthreads();
    scan[t] += u;
    __syncthreads();
  }
  excl[t] = scan[t] - h;
  lcur[t] = scan[t] - h;
  gbase[t] = (t < NBUCKB && h > 0) ? atomicAdd(&bcur[t], h) : 0;
  __syncthreads();
  for (int i = t; i < nval; i += 256) {
    int e = e0 + i;
    int d = dst[e];
    int p = atomicAdd(&lcur[d >> 8], 1);
    sorted[p] = ((unsigned)d << 16) | (unsigned)src[e];
  }
  __syncthreads();
  for (int i = t; i < nval; i += 256) {
    unsigned pk = sorted[i];
    int b = pk >> 24;                     // == dst>>8
    T[gbase[b] + (i - excl[b])] = pk;
  }
}

// Phase B: one block per bucket; place edges into exact CSR slots. Random
// writes confined to the bucket's ~16KB elist window (L2-local).
__global__ __launch_bounds__(256) void bucket_place_kernel(
    const unsigned* __restrict__ T, const int* __restrict__ offs,
    int* __restrict__ elist) {
  __shared__ int ncur[256];
  const int t = threadIdx.x;
  const int nb = blockIdx.x * 256;
  int node = nb + t;
  ncur[t] = (node < N) ? offs[node] : 0;
  __syncthreads();
  const int lo = offs[min(nb, N)];
  const int hi = offs[min(nb + 256, N)];
  for (int i = lo + t; i < hi; i += 256) {
    unsigned pk = T[i];
    int d = pk >> 16;
    int pos = atomicAdd(&ncur[d - nb], 1);
    elist[pos] = (int)(pk & 0xffffu);
  }
}

// ---------------- fp32 -> f16 convert (x) ----------------
__global__ void convert_kernel(const float* __restrict__ in, _Float16* __restrict__ out) {
  int i = blockIdx.x * 256 + threadIdx.x;
  if (i < N * 128 / 8) {
    float4 a = ((const float4*)in)[i * 2];
    float4 b = ((const float4*)in)[i * 2 + 1];
    f16x8 v;
    v[0] = (_Float16)a.x; v[1] = (_Float16)a.y; v[2] = (_Float16)a.z; v[3] = (_Float16)a.w;
    v[4] = (_Float16)b.x; v[5] = (_Float16)b.y; v[6] = (_Float16)b.z; v[7] = (_Float16)b.w;
    ((f16x8*)out)[i] = v;
  }
}

// ---------------- weight fragment tables ----------------
// Wf[((ct*KB+kb)*64+lane)*8+j] = Wcat[ct*16+(lane&15)][kb*32+(lane>>4)*8+j]
// KB=8: Wcat=[wl|wr] (K=256). KB=4: Wcat=wl (K=128).
template <int DOUT, int KB>
__global__ void build_wfrag_kernel(const float* __restrict__ wl,
                                   const float* __restrict__ wr,
                                   _Float16* __restrict__ wf) {
  constexpr int KSH = (KB == 8) ? 3 : 2;
  int idx = blockIdx.x * 256 + threadIdx.x;
  if (idx >= (DOUT / 16) * KB * 512) return;
  int j = idx & 7;
  int lane = (idx >> 3) & 63;
  int kb = (idx >> 9) & (KB - 1);
  int ct = idx >> (9 + KSH);
  int c = ct * 16 + (lane & 15);
  int k = kb * 32 + (lane >> 4) * 8 + j;
  float v;
  if (KB == 8) v = (k < 128) ? wl[c * 128 + k] : wr[c * 128 + (k - 128)];
  else v = wl[c * 128 + k];
  wf[idx] = (_Float16)v;
}

// ---------------- gathers: M[n,:] = mean of rows over CSR segment ----------------
// 128-wide: half-wave per node, lane covers 8B; unroll-8 edge ILP.
__global__ __launch_bounds__(256) void gather128_kernel(
    const _Float16* __restrict__ H, const int* __restrict__ offs,
    const int* __restrict__ elist, _Float16* __restrict__ M) {
  int node = blockIdx.x * 8 + (threadIdx.x >> 5);
  if (node >= N) return;
  int l = threadIdx.x & 31;
  const int e0 = offs[node];
  const int e1 = offs[node + 1];
  float a0 = 0.f, a1 = 0.f, a2 = 0.f, a3 = 0.f;
  int e = e0;
  for (; e + 8 <= e1; e += 8) {
    f16x4 v[8];
#pragma unroll
    for (int u = 0; u < 8; ++u)
      v[u] = *(const f16x4*)(H + (size_t)elist[e + u] * 128 + l * 4);
#pragma unroll
    for (int u = 0; u < 8; ++u) {
      a0 += (float)v[u][0]; a1 += (float)v[u][1];
      a2 += (float)v[u][2]; a3 += (float)v[u][3];
    }
  }
  for (; e < e1; ++e) {
    f16x4 v = *(const f16x4*)(H + (size_t)elist[e] * 128 + l * 4);
    a0 += (float)v[0]; a1 += (float)v[1]; a2 += (float)v[2]; a3 += (float)v[3];
  }
  float inv = 1.0f / (float)max(e1 - e0, 1);
  f16x4 o;
  o[0] = (_Float16)(a0 * inv); o[1] = (_Float16)(a1 * inv);
  o[2] = (_Float16)(a2 * inv); o[3] = (_Float16)(a3 * inv);
  *(f16x4*)(M + (size_t)node * 128 + l * 4) = o;
}

// 64-wide (layer-2 transform-first): 16 lanes per node.
__global__ __launch_bounds__(256) void gather64_kernel(
    const _Float16* __restrict__ Y, const int* __restrict__ offs,
    const int* __restrict__ elist, _Float16* __restrict__ M) {
  int node = blockIdx.x * 16 + (threadIdx.x >> 4);
  if (node >= N) return;
  int l = threadIdx.x & 15;
  const int e0 = offs[node];
  const int e1 = offs[node + 1];
  float a0 = 0.f, a1 = 0.f, a2 = 0.f, a3 = 0.f;
  int e = e0;
  for (; e + 8 <= e1; e += 8) {
    f16x4 v[8];
#pragma unroll
    for (int u = 0; u < 8; ++u)
      v[u] = *(const f16x4*)(Y + (size_t)elist[e + u] * 64 + l * 4);
#pragma unroll
    for (int u = 0; u < 8; ++u) {
      a0 += (float)v[u][0]; a1 += (float)v[u][1];
      a2 += (float)v[u][2]; a3 += (float)v[u][3];
    }
  }
  for (; e < e1; ++e) {
    f16x4 v = *(const f16x4*)(Y + (size_t)elist[e] * 64 + l * 4);
    a0 += (float)v[0]; a1 += (float)v[1]; a2 += (float)v[2]; a3 += (float)v[3];
  }
  float inv = 1.0f / (float)max(e1 - e0, 1);
  f16x4 o;
  o[0] = (_Float16)(a0 * inv); o[1] = (_Float16)(a1 * inv);
  o[2] = (_Float16)(a2 * inv); o[3] = (_Float16)(a3 * inv);
  *(f16x4*)(M + (size_t)node * 64 + l * 4) = o;
}

// ---------------- MFMA GEMM ----------------
// Wave tile 32 rows x 32 cols. DUAL: A=[M|H], K=256 (KB=8). else A=H, K=128
// (KB=4; A rows always 128-wide). ADDM: += M2[row,col] (f16, DOUT-wide).
template <int DOUT, int KB, bool DUAL, bool HASB, bool RELU, bool DROP,
          bool ADDM, bool OUTF32>
__global__ __launch_bounds__(256, 4) void mfma_gemm_kernel(
    const _Float16* __restrict__ Mm, const _Float16* __restrict__ Hh,
    const _Float16* __restrict__ Wf, const float* __restrict__ bias,
    const float* __restrict__ U, const _Float16* __restrict__ M2,
    void* __restrict__ outp) {
  constexpr int NCG = DOUT / 32;            // col-groups per block (4 or 2)
  constexpr int RPB = 32 * (4 / NCG);       // rows per block (32 or 64)
  const int lane = threadIdx.x & 63;
  const int w = threadIdx.x >> 6;
  const int colgrp = w % NCG;
  const int rowsel = w / NCG;
  const int n16 = lane & 15;
  const int q = lane >> 4;
  const int rowbase = blockIdx.x * RPB + rowsel * 32;
  const int colbase = colgrp * 32;

  f32x4 acc[2][2];
#pragma unroll
  for (int h = 0; h < 2; ++h)
#pragma unroll
    for (int ct = 0; ct < 2; ++ct) acc[h][ct] = (f32x4){0.f, 0.f, 0.f, 0.f};

  int ar0 = min(rowbase + n16, N - 1);       // clamp feeds only discarded rows
  int ar1 = min(rowbase + 16 + n16, N - 1);
  const _Float16* pM0 = Mm + (size_t)ar0 * 128 + q * 8;
  const _Float16* pM1 = Mm + (size_t)ar1 * 128 + q * 8;
  const _Float16* pH0 = Hh + (size_t)ar0 * 128 + q * 8;
  const _Float16* pH1 = Hh + (size_t)ar1 * 128 + q * 8;

#pragma unroll
  for (int kb = 0; kb < KB; ++kb) {
    const _Float16* b0;
    const _Float16* b1;
    int ko;
    if (DUAL) {
      ko = (kb & (KB / 2 - 1)) * 32;
      b0 = (kb < KB / 2) ? pM0 : pH0;
      b1 = (kb < KB / 2) ? pM1 : pH1;
    } else {
      ko = kb * 32;
      b0 = pH0;
      b1 = pH1;
    }
    f16x8 a0 = *(const f16x8*)(b0 + ko);
    f16x8 a1 = *(const f16x8*)(b1 + ko);
#pragma unroll
    for (int ct = 0; ct < 2; ++ct) {
      const int ctg = colgrp * 2 + ct;
      f16x8 b = *(const f16x8*)(Wf + ((size_t)(ctg * KB + kb) * 64 + lane) * 8);
      acc[0][ct] = __builtin_amdgcn_mfma_f32_16x16x32_f16(a0, b, acc[0][ct], 0, 0, 0);
      acc[1][ct] = __builtin_amdgcn_mfma_f32_16x16x32_f16(a1, b, acc[1][ct], 0, 0, 0);
    }
  }

  // epilogue; C/D layout: col = lane&15, row = (lane>>4)*4 + reg
#pragma unroll
  for (int h = 0; h < 2; ++h) {
#pragma unroll
    for (int ct = 0; ct < 2; ++ct) {
      const int col = colbase + ct * 16 + n16;
      const float bv = HASB ? bias[col] : 0.0f;
#pragma unroll
      for (int r = 0; r < 4; ++r) {
        int row = rowbase + h * 16 + q * 4 + r;
        if (row < N) {
          float v = acc[h][ct][r] + bv;
          if (ADDM) v += (float)M2[(size_t)row * DOUT + col];
          if (RELU) v = fmaxf(v, 0.f);
          if (DROP) {
            float u = U[(size_t)row * 128 + col];
            v *= (u >= 0.3f) ? (1.0f / 0.7f) : 0.0f;
          }
          if (OUTF32) ((float*)outp)[(size_t)row * DOUT + col] = v;
          else ((_Float16*)outp)[(size_t)row * DOUT + col] = (_Float16)v;
        }
      }
    }
  }
}

extern "C" void kernel_launch(void* const* d_in, const int* in_sizes, int n_in,
                              void* d_out, int out_size, void* d_ws, size_t ws_size,
                              hipStream_t stream) {
  const float* x   = (const float*)d_in[0];
  const float* u1  = (const float*)d_in[1];
  const float* u2  = (const float*)d_in[2];
  const float* wl0 = (const float*)d_in[3];
  const float* bl0 = (const float*)d_in[4];
  const float* wr0 = (const float*)d_in[5];
  const float* wl1 = (const float*)d_in[6];
  const float* bl1 = (const float*)d_in[7];
  const float* wr1 = (const float*)d_in[8];
  const float* wl2 = (const float*)d_in[9];
  const float* bl2 = (const float*)d_in[10];
  const float* wr2 = (const float*)d_in[11];
  const int* edge  = (const int*)d_in[12];
  const int* src = edge;
  const int* dst = edge + E;

  // workspace layout
  _Float16* HA = (_Float16*)d_ws;                  // N x 128 f16
  _Float16* HB = HA + (size_t)N * 128;             // N x 128 f16
  _Float16* M16 = HB + (size_t)N * 128;            // N x 128 f16 (also Y2)
  _Float16* M2 = M16 + (size_t)N * 128;            // N x 64 f16
  int* deg    = (int*)(M2 + (size_t)N * 64);
  int* offs   = deg + N;                           // N+1
  int* elist  = offs + N + 1;                      // E
  unsigned* T = (unsigned*)(elist + E);            // E packed (dst<<16|src)
  int* bcur     = (int*)(T + E);                   // NBUCKB
  int* blocksum = bcur + NBUCKB;                   // NB
  int* blockoff = blocksum + NB;                   // NB
  uintptr_t p = (uintptr_t)(blockoff + NB);
  p = (p + 15) & ~(uintptr_t)15;
  _Float16* wf0  = (_Float16*)p;                   // 8*8*512
  _Float16* wf1  = wf0 + 8 * 8 * 512;
  _Float16* wf2l = wf1 + 8 * 8 * 512;              // 4*4*512
  _Float16* wf2r = wf2l + 4 * 4 * 512;

  // CSR build
  hipMemsetAsync(deg, 0, (size_t)N * sizeof(int), stream);
  hist_kernel<<<(E + 255) / 256, 256, 0, stream>>>(dst, deg);
  scan_partial_kernel<<<NB, 256, 0, stream>>>(deg, blocksum);
  scan_sums_kernel<<<1, 256, 0, stream>>>(blocksum, blockoff);
  scan_final_kernel<<<NB, 256, 0, stream>>>(deg, blockoff, offs);
  bucket_cursor_init<<<(NBUCKB + 255) / 256, 256, 0, stream>>>(offs, bcur);
  bucket_scatter_kernel<<<NEB, 256, 0, stream>>>(src, dst, bcur, T);
  bucket_place_kernel<<<NBUCKB, 256, 0, stream>>>(T, offs, elist);

  // converts
  convert_kernel<<<(N * 128 / 8 + 255) / 256, 256, 0, stream>>>(x, HA);
  build_wfrag_kernel<128, 8><<<128, 256, 0, stream>>>(wl0, wr0, wf0);
  build_wfrag_kernel<128, 8><<<128, 256, 0, stream>>>(wl1, wr1, wf1);
  build_wfrag_kernel<64, 4><<<32, 256, 0, stream>>>(wl2, nullptr, wf2l);
  build_wfrag_kernel<64, 4><<<32, 256, 0, stream>>>(wr2, nullptr, wf2r);

  const int GG128 = (N + 7) / 8;
  const int GG64  = (N + 15) / 16;
  const int GM128 = (N + 31) / 32;     // 32 rows/block
  const int GM64  = (N + 63) / 64;     // 64 rows/block

  // ---- Layer 0 ----
  gather128_kernel<<<GG128, 256, 0, stream>>>(HA, offs, elist, M16);
  mfma_gemm_kernel<128, 8, true, true, true, true, false, false>
      <<<GM128, 256, 0, stream>>>(M16, HA, wf0, bl0, u1, nullptr, HB);
  // ---- Layer 1 ----
  gather128_kernel<<<GG128, 256, 0, stream>>>(HB, offs, elist, M16);
  mfma_gemm_kernel<128, 8, true, true, true, true, false, false>
      <<<GM128, 256, 0, stream>>>(M16, HB, wf1, bl1, u2, nullptr, HA);
  // ---- Layer 2 (transform-first: Y2 = H@wl2^T, gather 64-wide) ----
  mfma_gemm_kernel<64, 4, false, false, false, false, false, false>
      <<<GM64, 256, 0, stream>>>(nullptr, HA, wf2l, nullptr, nullptr, nullptr, M16);
  gather64_kernel<<<GG64, 256, 0, stream>>>(M16, offs, elist, M2);
  mfma_gemm_kernel<64, 4, false, true, false, false, true, true>
      <<<GM64, 256, 0, stream>>>(nullptr, HA, wf2r, bl2, nullptr, M2, d_out);
}

// Round 7
// 341.880 us; speedup vs baseline: 11.0849x; 1.0677x over previous
//
#include <hip/hip_runtime.h>

// GraphSAGE 3-layer forward, MI355X. Round 7:
//   R6 profile: top-5 all harness ws-poison fills (41us, 256MB @ 6.5TB/s) ->
//   every real kernel <41us; pipeline is long-tail bound (~20 serialized
//   dispatches). Fixes: (1) CSR build without N-wide hist (bucket hist 196
//   counters + bucket_place derives per-node offs in LDS): 6->4 dispatches;
//   (2) convert + 4 wfrag builds fused into one setup kernel: 5->1;
//   (3) gather128 wave-per-node (2x independent waves, no intra-wave degree
//   imbalance). 13 dispatches total.

constexpr int N = 50000;
constexpr int E = 800000;
constexpr int NBUCK = (N + 255) / 256;    // 196 dst-buckets (256 nodes each)
constexpr int CE = 4096;                  // edges per chunk
constexpr int NEB = (E + CE - 1) / CE;    // 196
static_assert(N <= 65536, "u16 packing");

typedef _Float16 f16x8 __attribute__((ext_vector_type(8)));
typedef _Float16 f16x2 __attribute__((ext_vector_type(2)));
typedef float f32x4 __attribute__((ext_vector_type(4)));

// ---------------- CSR build (bucketized, no N-wide hist) ----------------

// per-bucket edge totals (LDS-aggregated)
__global__ __launch_bounds__(256) void bucket_hist_kernel(
    const int* __restrict__ dst, int* __restrict__ btot) {
  __shared__ int h[NBUCK];
  for (int i = threadIdx.x; i < NBUCK; i += 256) h[i] = 0;
  __syncthreads();
  const int e0 = blockIdx.x * CE;
  const int nval = min(CE, E - e0);
  for (int i = threadIdx.x; i < nval; i += 256) atomicAdd(&h[dst[e0 + i] >> 8], 1);
  __syncthreads();
  for (int i = threadIdx.x; i < NBUCK; i += 256)
    if (h[i]) atomicAdd(&btot[i], h[i]);
}

// exclusive scan of 196 bucket totals -> bbase, bcur
__global__ __launch_bounds__(256) void scan_bucket_kernel(
    const int* __restrict__ btot, int* __restrict__ bbase, int* __restrict__ bcur) {
  __shared__ int s[256];
  const int t = threadIdx.x;
  int v = (t < NBUCK) ? btot[t] : 0;
  s[t] = v;
  __syncthreads();
  for (int off = 1; off < 256; off <<= 1) {
    int u = (t >= off) ? s[t - off] : 0;
    __syncthreads();
    s[t] += u;
    __syncthreads();
  }
  if (t < NBUCK) { bbase[t] = s[t] - v; bcur[t] = s[t] - v; }
}

// Phase A: LDS counting sort of a 4096-edge chunk by dst>>8; write grouped
// runs of packed (dst<<16|src) into bucket regions of T (near-coalesced).
__global__ __launch_bounds__(256) void bucket_scatter_kernel(
    const int* __restrict__ src, const int* __restrict__ dst,
    int* __restrict__ bcur, unsigned* __restrict__ T) {
  __shared__ unsigned sorted[CE];
  __shared__ int hist[256], scan[256], excl[256], lcur[256], gbase[256];
  const int t = threadIdx.x;
  const int e0 = blockIdx.x * CE;
  const int nval = min(CE, E - e0);
  hist[t] = 0;
  __syncthreads();
  for (int i = t; i < nval; i += 256) atomicAdd(&hist[dst[e0 + i] >> 8], 1);
  __syncthreads();
  const int h = hist[t];
  scan[t] = h;
  __syncthreads();
  for (int off = 1; off < 256; off <<= 1) {
    int u = (t >= off) ? scan[t - off] : 0;
    __syncthreads();
    scan[t] += u;
    __syncthreads();
  }
  excl[t] = scan[t] - h;
  lcur[t] = scan[t] - h;
  gbase[t] = (t < NBUCK && h > 0) ? atomicAdd(&bcur[t], h) : 0;
  __syncthreads();
  for (int i = t; i < nval; i += 256) {
    int e = e0 + i;
    int d = dst[e];
    int p = atomicAdd(&lcur[d >> 8], 1);
    sorted[p] = ((unsigned)d << 16) | (unsigned)src[e];
  }
  __syncthreads();
  for (int i = t; i < nval; i += 256) {
    unsigned pk = sorted[i];
    int b = pk >> 24;                     // == dst>>8
    T[gbase[b] + (i - excl[b])] = pk;
  }
}

// Phase B: one block per bucket. Derive per-node offsets (LDS hist + scan),
// write offs, then place edges into exact CSR slots (16KB L2-local window).
__global__ __launch_bounds__(256) void bucket_place_kernel(
    const unsigned* __restrict__ T, const int* __restrict__ bbase,
    const int* __restrict__ btot, int* __restrict__ offs, int* __restrict__ elist) {
  __shared__ int dcnt[256], s[256], ncur[256];
  const int t = threadIdx.x;
  const int b = blockIdx.x;
  const int lo = bbase[b];
  const int hi = lo + btot[b];
  dcnt[t] = 0;
  __syncthreads();
  for (int i = lo + t; i < hi; i += 256) atomicAdd(&dcnt[(T[i] >> 16) & 255], 1);
  __syncthreads();
  const int v = dcnt[t];
  s[t] = v;
  __syncthreads();
  for (int off = 1; off < 256; off <<= 1) {
    int u = (t >= off) ? s[t - off] : 0;
    __syncthreads();
    s[t] += u;
    __syncthreads();
  }
  const int base = lo + s[t] - v;   // exclusive within bucket + bucket base
  const int node = b * 256 + t;
  if (node < N) offs[node] = base;
  ncur[t] = base;
  __syncthreads();
  for (int i = lo + t; i < hi; i += 256) {
    unsigned pk = T[i];
    int pos = atomicAdd(&ncur[(pk >> 16) & 255], 1);
    elist[pos] = (int)(pk & 0xffffu);
  }
  if (b == NBUCK - 1 && t == 0) offs[N] = E;
}

// ---------------- fused setup: x->f16 convert + 4 weight fragment tables ----
// Wf[((ct*KB+kb)*64+lane)*8+j] = Wcat[ct*16+(lane&15)][kb*32+(lane>>4)*8+j]
__device__ inline void wfrag_build(int idx, int KB, const float* wl,
                                   const float* wr, _Float16* wf) {
  int j = idx & 7;
  int lane = (idx >> 3) & 63;
  int kb = (idx >> 9) % KB;
  int ct = (idx >> 9) / KB;
  int c = ct * 16 + (lane & 15);
  int k = kb * 32 + (lane >> 4) * 8 + j;
  float v = (k < 128) ? wl[c * 128 + k] : wr[c * 128 + (k - 128)];
  wf[idx] = (_Float16)v;
}

constexpr int CONVB = (N * 128 / 8 + 255) / 256;   // 3125 convert blocks

__global__ __launch_bounds__(256) void setup_kernel(
    const float* __restrict__ x,
    const float* __restrict__ wl0, const float* __restrict__ wr0,
    const float* __restrict__ wl1, const float* __restrict__ wr1,
    const float* __restrict__ wl2, const float* __restrict__ wr2,
    _Float16* __restrict__ HA, _Float16* __restrict__ wf0,
    _Float16* __restrict__ wf1, _Float16* __restrict__ wf2l,
    _Float16* __restrict__ wf2r) {
  const int b = blockIdx.x;
  const int t = threadIdx.x;
  if (b < CONVB) {
    int i = b * 256 + t;                  // one thread per 8 elems
    if (i < N * 128 / 8) {
      float4 a = ((const float4*)x)[i * 2];
      float4 c = ((const float4*)x)[i * 2 + 1];
      f16x8 v;
      v[0] = (_Float16)a.x; v[1] = (_Float16)a.y; v[2] = (_Float16)a.z; v[3] = (_Float16)a.w;
      v[4] = (_Float16)c.x; v[5] = (_Float16)c.y; v[6] = (_Float16)c.z; v[7] = (_Float16)c.w;
      ((f16x8*)HA)[i] = v;
    }
  } else if (b < CONVB + 128) {           // wf0: 8 ct * 8 kb * 512
    wfrag_build((b - CONVB) * 256 + t, 8, wl0, wr0, wf0);
  } else if (b < CONVB + 256) {           // wf1
    wfrag_build((b - CONVB - 128) * 256 + t, 8, wl1, wr1, wf1);
  } else if (b < CONVB + 288) {           // wf2l: 4 ct * 4 kb * 512 (K=128)
    wfrag_build((b - CONVB - 256) * 256 + t, 4, wl2, wl2, wf2l);
  } else {                                // wf2r
    wfrag_build((b - CONVB - 288) * 256 + t, 4, wr2, wr2, wf2r);
  }
}

// ---------------- gathers: M[n,:] = mean of rows over CSR segment ----------
// 128-wide: one wave (64 lanes x f16x2) per node; elist chunk prefetched.
__global__ __launch_bounds__(256) void gather128_kernel(
    const _Float16* __restrict__ H, const int* __restrict__ offs,
    const int* __restrict__ elist, _Float16* __restrict__ M) {
  int node = blockIdx.x * 4 + (threadIdx.x >> 6);
  if (node >= N) return;
  int l = threadIdx.x & 63;
  const int e0 = offs[node];
  const int e1 = offs[node + 1];
  float a0 = 0.f, a1 = 0.f;
  int e = e0;
  for (; e + 8 <= e1; e += 8) {
    int s[8];
#pragma unroll
    for (int u = 0; u < 8; ++u) s[u] = elist[e + u];
    f16x2 v[8];
#pragma unroll
    for (int u = 0; u < 8; ++u)
      v[u] = *(const f16x2*)(H + (size_t)s[u] * 128 + l * 2);
#pragma unroll
    for (int u = 0; u < 8; ++u) { a0 += (float)v[u][0]; a1 += (float)v[u][1]; }
  }
  for (; e < e1; ++e) {
    f16x2 v = *(const f16x2*)(H + (size_t)elist[e] * 128 + l * 2);
    a0 += (float)v[0]; a1 += (float)v[1];
  }
  float inv = 1.0f / (float)max(e1 - e0, 1);
  f16x2 o;
  o[0] = (_Float16)(a0 * inv); o[1] = (_Float16)(a1 * inv);
  *(f16x2*)(M + (size_t)node * 128 + l * 2) = o;
}

// 64-wide (layer-2 transform-first): half-wave (32 lanes x f16x2) per node.
__global__ __launch_bounds__(256) void gather64_kernel(
    const _Float16* __restrict__ Y, const int* __restrict__ offs,
    const int* __restrict__ elist, _Float16* __restrict__ M) {
  int node = blockIdx.x * 8 + (threadIdx.x >> 5);
  if (node >= N) return;
  int l = threadIdx.x & 31;
  const int e0 = offs[node];
  const int e1 = offs[node + 1];
  float a0 = 0.f, a1 = 0.f;
  int e = e0;
  for (; e + 8 <= e1; e += 8) {
    int s[8];
#pragma unroll
    for (int u = 0; u < 8; ++u) s[u] = elist[e + u];
    f16x2 v[8];
#pragma unroll
    for (int u = 0; u < 8; ++u)
      v[u] = *(const f16x2*)(Y + (size_t)s[u] * 64 + l * 2);
#pragma unroll
    for (int u = 0; u < 8; ++u) { a0 += (float)v[u][0]; a1 += (float)v[u][1]; }
  }
  for (; e < e1; ++e) {
    f16x2 v = *(const f16x2*)(Y + (size_t)elist[e] * 64 + l * 2);
    a0 += (float)v[0]; a1 += (float)v[1];
  }
  float inv = 1.0f / (float)max(e1 - e0, 1);
  f16x2 o;
  o[0] = (_Float16)(a0 * inv); o[1] = (_Float16)(a1 * inv);
  *(f16x2*)(M + (size_t)node * 64 + l * 2) = o;
}

// ---------------- MFMA GEMM ----------------
// Wave tile 32 rows x 32 cols. DUAL: A=[M|H], K=256 (KB=8). else A=H, K=128
// (KB=4; A rows always 128-wide). ADDM: += M2[row,col] (f16, DOUT-wide).
template <int DOUT, int KB, bool DUAL, bool HASB, bool RELU, bool DROP,
          bool ADDM, bool OUTF32>
__global__ __launch_bounds__(256, 4) void mfma_gemm_kernel(
    const _Float16* __restrict__ Mm, const _Float16* __restrict__ Hh,
    const _Float16* __restrict__ Wf, const float* __restrict__ bias,
    const float* __restrict__ U, const _Float16* __restrict__ M2,
    void* __restrict__ outp) {
  constexpr int NCG = DOUT / 32;            // col-groups per block (4 or 2)
  constexpr int RPB = 32 * (4 / NCG);       // rows per block (32 or 64)
  const int lane = threadIdx.x & 63;
  const int w = threadIdx.x >> 6;
  const int colgrp = w % NCG;
  const int rowsel = w / NCG;
  const int n16 = lane & 15;
  const int q = lane >> 4;
  const int rowbase = blockIdx.x * RPB + rowsel * 32;
  const int colbase = colgrp * 32;

  f32x4 acc[2][2];
#pragma unroll
  for (int h = 0; h < 2; ++h)
#pragma unroll
    for (int ct = 0; ct < 2; ++ct) acc[h][ct] = (f32x4){0.f, 0.f, 0.f, 0.f};

  int ar0 = min(rowbase + n16, N - 1);       // clamp feeds only discarded rows
  int ar1 = min(rowbase + 16 + n16, N - 1);
  const _Float16* pM0 = Mm + (size_t)ar0 * 128 + q * 8;
  const _Float16* pM1 = Mm + (size_t)ar1 * 128 + q * 8;
  const _Float16* pH0 = Hh + (size_t)ar0 * 128 + q * 8;
  const _Float16* pH1 = Hh + (size_t)ar1 * 128 + q * 8;

  typedef _Float16 f16x8l __attribute__((ext_vector_type(8)));
#pragma unroll
  for (int kb = 0; kb < KB; ++kb) {
    const _Float16* b0;
    const _Float16* b1;
    int ko;
    if (DUAL) {
      ko = (kb & (KB / 2 - 1)) * 32;
      b0 = (kb < KB / 2) ? pM0 : pH0;
      b1 = (kb < KB / 2) ? pM1 : pH1;
    } else {
      ko = kb * 32;
      b0 = pH0;
      b1 = pH1;
    }
    f16x8l a0 = *(const f16x8l*)(b0 + ko);
    f16x8l a1 = *(const f16x8l*)(b1 + ko);
#pragma unroll
    for (int ct = 0; ct < 2; ++ct) {
      const int ctg = colgrp * 2 + ct;
      f16x8l b = *(const f16x8l*)(Wf + ((size_t)(ctg * KB + kb) * 64 + lane) * 8);
      acc[0][ct] = __builtin_amdgcn_mfma_f32_16x16x32_f16(a0, b, acc[0][ct], 0, 0, 0);
      acc[1][ct] = __builtin_amdgcn_mfma_f32_16x16x32_f16(a1, b, acc[1][ct], 0, 0, 0);
    }
  }

  // epilogue; C/D layout: col = lane&15, row = (lane>>4)*4 + reg
#pragma unroll
  for (int h = 0; h < 2; ++h) {
#pragma unroll
    for (int ct = 0; ct < 2; ++ct) {
      const int col = colbase + ct * 16 + n16;
      const float bv = HASB ? bias[col] : 0.0f;
#pragma unroll
      for (int r = 0; r < 4; ++r) {
        int row = rowbase + h * 16 + q * 4 + r;
        if (row < N) {
          float v = acc[h][ct][r] + bv;
          if (ADDM) v += (float)M2[(size_t)row * DOUT + col];
          if (RELU) v = fmaxf(v, 0.f);
          if (DROP) {
            float u = U[(size_t)row * 128 + col];
            v *= (u >= 0.3f) ? (1.0f / 0.7f) : 0.0f;
          }
          if (OUTF32) ((float*)outp)[(size_t)row * DOUT + col] = v;
          else ((_Float16*)outp)[(size_t)row * DOUT + col] = (_Float16)v;
        }
      }
    }
  }
}

extern "C" void kernel_launch(void* const* d_in, const int* in_sizes, int n_in,
                              void* d_out, int out_size, void* d_ws, size_t ws_size,
                              hipStream_t stream) {
  const float* x   = (const float*)d_in[0];
  const float* u1  = (const float*)d_in[1];
  const float* u2  = (const float*)d_in[2];
  const float* wl0 = (const float*)d_in[3];
  const float* bl0 = (const float*)d_in[4];
  const float* wr0 = (const float*)d_in[5];
  const float* wl1 = (const float*)d_in[6];
  const float* bl1 = (const float*)d_in[7];
  const float* wr1 = (const float*)d_in[8];
  const float* wl2 = (const float*)d_in[9];
  const float* bl2 = (const float*)d_in[10];
  const float* wr2 = (const float*)d_in[11];
  const int* edge  = (const int*)d_in[12];
  const int* src = edge;
  const int* dst = edge + E;

  // workspace layout
  _Float16* HA = (_Float16*)d_ws;                  // N x 128 f16
  _Float16* HB = HA + (size_t)N * 128;             // N x 128 f16
  _Float16* M16 = HB + (size_t)N * 128;            // N x 128 f16 (also Y2)
  _Float16* M2 = M16 + (size_t)N * 128;            // N x 64 f16
  int* offs   = (int*)(M2 + (size_t)N * 64);       // N+1
  int* elist  = offs + N + 1;                      // E
  unsigned* T = (unsigned*)(elist + E);            // E packed (dst<<16|src)
  int* btot   = (int*)(T + E);                     // NBUCK
  int* bbase  = btot + NBUCK;                      // NBUCK
  int* bcur   = bbase + NBUCK;                     // NBUCK
  uintptr_t p = (uintptr_t)(bcur + NBUCK);
  p = (p + 15) & ~(uintptr_t)15;
  _Float16* wf0  = (_Float16*)p;                   // 8*8*512
  _Float16* wf1  = wf0 + 8 * 8 * 512;
  _Float16* wf2l = wf1 + 8 * 8 * 512;              // 4*4*512
  _Float16* wf2r = wf2l + 4 * 4 * 512;

  // CSR build: 4 dispatches + tiny memset
  hipMemsetAsync(btot, 0, NBUCK * sizeof(int), stream);
  bucket_hist_kernel<<<NEB, 256, 0, stream>>>(dst, btot);
  scan_bucket_kernel<<<1, 256, 0, stream>>>(btot, bbase, bcur);
  bucket_scatter_kernel<<<NEB, 256, 0, stream>>>(src, dst, bcur, T);
  bucket_place_kernel<<<NBUCK, 256, 0, stream>>>(T, bbase, btot, offs, elist);

  // fused convert + weight-fragment builds (1 dispatch)
  setup_kernel<<<CONVB + 320, 256, 0, stream>>>(
      x, wl0, wr0, wl1, wr1, wl2, wr2, HA, wf0, wf1, wf2l, wf2r);

  const int GG128 = (N + 3) / 4;       // wave per node
  const int GG64  = (N + 7) / 8;       // half-wave per node
  const int GM128 = (N + 31) / 32;     // 32 rows/block
  const int GM64  = (N + 63) / 64;     // 64 rows/block

  // ---- Layer 0 ----
  gather128_kernel<<<GG128, 256, 0, stream>>>(HA, offs, elist, M16);
  mfma_gemm_kernel<128, 8, true, true, true, true, false, false>
      <<<GM128, 256, 0, stream>>>(M16, HA, wf0, bl0, u1, nullptr, HB);
  // ---- Layer 1 ----
  gather128_kernel<<<GG128, 256, 0, stream>>>(HB, offs, elist, M16);
  mfma_gemm_kernel<128, 8, true, true, true, true, false, false>
      <<<GM128, 256, 0, stream>>>(M16, HB, wf1, bl1, u2, nullptr, HA);
  // ---- Layer 2 (transform-first: Y2 = H@wl2^T, gather 64-wide) ----
  mfma_gemm_kernel<64, 4, false, false, false, false, false, false>
      <<<GM64, 256, 0, stream>>>(nullptr, HA, wf2l, nullptr, nullptr, nullptr, M16);
  gather64_kernel<<<GG64, 256, 0, stream>>>(M16, offs, elist, M2);
  mfma_gemm_kernel<64, 4, false, true, false, false, true, true>
      <<<GM64, 256, 0, stream>>>(nullptr, HA, wf2r, bl2, nullptr, M2, d_out);
}

// Round 9
// 308.472 us; speedup vs baseline: 12.2854x; 1.1083x over previous
//
#include <hip/hip_runtime.h>

// GraphSAGE 3-layer forward, MI355X. Round 9 (= round 8 + wfZ sizing fix):
//   R8 failed: wfZ table is 8ct*4kb*512 = 16384 entries = 64 blocks, but the
//   setup grid gave that branch only 32 -> cols 64-127 of layer-2 GEMM used
//   0xAA-poisoned weights (absmax 9.7). Fix: 64 blocks, grid CONVB+321.
//   Structure: padded-slab CSR (scatter+place only), fused setup, unroll-16
//   gathers, layer-2 single GEMM (Y2 f16 | F f32) + gather64_add. 9 dispatches.

constexpr int N = 50000;
constexpr int E = 800000;
constexpr int NBUCK = (N + 255) / 256;    // 196 dst-buckets (256 nodes each)
constexpr int CE = 4096;                  // edges per scatter chunk
constexpr int NEB = (E + CE - 1) / CE;    // 196
constexpr int SLOT = 5120;                // padded slab per bucket (exp 4096, sd 64)
static_assert(N <= 65536, "u16 packing");

typedef _Float16 f16x8 __attribute__((ext_vector_type(8)));
typedef _Float16 f16x2 __attribute__((ext_vector_type(2)));
typedef float f32x4 __attribute__((ext_vector_type(4)));

// ---------------- CSR build (padded buckets; no global hist/scan) ----------

// Phase A: LDS counting sort of a 4096-edge chunk by dst>>8; append grouped
// runs of packed (dst<<16|src) into each bucket's padded slab of T.
__global__ __launch_bounds__(256) void bucket_scatter_kernel(
    const int* __restrict__ src, const int* __restrict__ dst,
    int* __restrict__ bcur, unsigned* __restrict__ T) {
  __shared__ unsigned sorted[CE];
  __shared__ int hist[256], scan[256], excl[256], lcur[256], gbase[256];
  const int t = threadIdx.x;
  const int e0 = blockIdx.x * CE;
  const int nval = min(CE, E - e0);
  hist[t] = 0;
  __syncthreads();
  for (int i = t; i < nval; i += 256) atomicAdd(&hist[dst[e0 + i] >> 8], 1);
  __syncthreads();
  const int h = hist[t];
  scan[t] = h;
  __syncthreads();
  for (int off = 1; off < 256; off <<= 1) {
    int u = (t >= off) ? scan[t - off] : 0;
    __syncthreads();
    scan[t] += u;
    __syncthreads();
  }
  excl[t] = scan[t] - h;
  lcur[t] = scan[t] - h;
  gbase[t] = (t < NBUCK && h > 0) ? atomicAdd(&bcur[t], h) : 0;
  __syncthreads();
  for (int i = t; i < nval; i += 256) {
    int e = e0 + i;
    int d = dst[e];
    int p = atomicAdd(&lcur[d >> 8], 1);
    sorted[p] = ((unsigned)d << 16) | (unsigned)src[e];
  }
  __syncthreads();
  for (int i = t; i < nval; i += 256) {
    unsigned pk = sorted[i];
    int b = pk >> 24;                     // == dst>>8
    T[gbase[b] + (i - excl[b])] = pk;
  }
}

// Phase B: one block per bucket. Derive per-node offsets/degrees (LDS hist +
// scan), write offs+deg, place edges into exact slots of the padded elist.
__global__ __launch_bounds__(256) void bucket_place_kernel(
    const unsigned* __restrict__ T, const int* __restrict__ bcur,
    int* __restrict__ offs, int* __restrict__ deg, int* __restrict__ elist) {
  __shared__ int dcnt[256], s[256], ncur[256];
  const int t = threadIdx.x;
  const int b = blockIdx.x;
  const int lo = b * SLOT;
  const int hi = bcur[b];                 // lo + edges-in-bucket
  dcnt[t] = 0;
  __syncthreads();
  for (int i = lo + t; i < hi; i += 256) atomicAdd(&dcnt[(T[i] >> 16) & 255], 1);
  __syncthreads();
  const int v = dcnt[t];
  s[t] = v;
  __syncthreads();
  for (int off = 1; off < 256; off <<= 1) {
    int u = (t >= off) ? s[t - off] : 0;
    __syncthreads();
    s[t] += u;
    __syncthreads();
  }
  const int base = lo + s[t] - v;         // within-bucket exclusive + slab base
  const int node = b * 256 + t;
  if (node < N) { offs[node] = base; deg[node] = v; }
  ncur[t] = base;
  __syncthreads();
  for (int i = lo + t; i < hi; i += 256) {
    unsigned pk = T[i];
    int pos = atomicAdd(&ncur[(pk >> 16) & 255], 1);
    elist[pos] = (int)(pk & 0xffffu);
  }
}

// ---------------- fused setup: convert + wfrag tables + bcur init ----------
// Wf[((ct*KB+kb)*64+lane)*8+j] = Wcat[ct*16+(lane&15)][kb*32+(lane>>4)*8+j]
__device__ inline void wfrag_build(int idx, int KB, const float* wl,
                                   const float* wr, _Float16* wf) {
  int j = idx & 7;
  int lane = (idx >> 3) & 63;
  int kb = (idx >> 9) % KB;
  int ct = (idx >> 9) / KB;
  int c = ct * 16 + (lane & 15);
  int k = kb * 32 + (lane >> 4) * 8 + j;
  float v = (k < 128) ? wl[c * 128 + k] : wr[c * 128 + (k - 128)];
  wf[idx] = (_Float16)v;
}

constexpr int CONVB = (N * 128 / 8 + 255) / 256;   // 3125 convert blocks

__global__ __launch_bounds__(256) void setup_kernel(
    const float* __restrict__ x,
    const float* __restrict__ wl0, const float* __restrict__ wr0,
    const float* __restrict__ wl1, const float* __restrict__ wr1,
    const float* __restrict__ wl2, const float* __restrict__ wr2,
    _Float16* __restrict__ HA, _Float16* __restrict__ wf0,
    _Float16* __restrict__ wf1, _Float16* __restrict__ wfZ,
    int* __restrict__ bcur) {
  const int b = blockIdx.x;
  const int t = threadIdx.x;
  if (b < CONVB) {
    int i = b * 256 + t;                  // one thread per 8 elems
    if (i < N * 128 / 8) {
      float4 a = ((const float4*)x)[i * 2];
      float4 c = ((const float4*)x)[i * 2 + 1];
      f16x8 v;
      v[0] = (_Float16)a.x; v[1] = (_Float16)a.y; v[2] = (_Float16)a.z; v[3] = (_Float16)a.w;
      v[4] = (_Float16)c.x; v[5] = (_Float16)c.y; v[6] = (_Float16)c.z; v[7] = (_Float16)c.w;
      ((f16x8*)HA)[i] = v;
    }
  } else if (b < CONVB + 128) {           // wf0: [wl0|wr0], K=256 (32768 = 128 blk)
    wfrag_build((b - CONVB) * 256 + t, 8, wl0, wr0, wf0);
  } else if (b < CONVB + 256) {           // wf1: [wl1|wr1]
    wfrag_build((b - CONVB - 128) * 256 + t, 8, wl1, wr1, wf1);
  } else if (b < CONVB + 320) {           // wfZ: 8ct*4kb*512 = 16384 = 64 blocks
    int idx = (b - CONVB - 256) * 256 + t;
    int j = idx & 7;
    int lane = (idx >> 3) & 63;
    int kb = (idx >> 9) & 3;
    int ct = idx >> 11;                   // 0..7
    int c = ct * 16 + (lane & 15);
    int k = kb * 32 + (lane >> 4) * 8 + j;
    float v = (c < 64) ? wl2[c * 128 + k] : wr2[(c - 64) * 128 + k];
    wfZ[idx] = (_Float16)v;
  } else {                                // bcur init (1 block)
    if (t < NBUCK) bcur[t] = t * SLOT;
  }
}

// ---------------- gather128: M[n,:] = mean of H[src,:] over segment --------
// One wave (64 lanes x f16x2) per node; unroll-16 (avg degree = 16).
__global__ __launch_bounds__(256) void gather128_kernel(
    const _Float16* __restrict__ H, const int* __restrict__ offs,
    const int* __restrict__ deg, const int* __restrict__ elist,
    _Float16* __restrict__ M) {
  int node = blockIdx.x * 4 + (threadIdx.x >> 6);
  if (node >= N) return;
  int l = threadIdx.x & 63;
  const int e0 = offs[node];
  const int d = deg[node];
  const int e1 = e0 + d;
  float a0 = 0.f, a1 = 0.f;
  int e = e0;
  for (; e + 16 <= e1; e += 16) {
    int s[16];
#pragma unroll
    for (int u = 0; u < 16; ++u) s[u] = elist[e + u];
    f16x2 v[16];
#pragma unroll
    for (int u = 0; u < 16; ++u)
      v[u] = *(const f16x2*)(H + (size_t)s[u] * 128 + l * 2);
#pragma unroll
    for (int u = 0; u < 16; ++u) { a0 += (float)v[u][0]; a1 += (float)v[u][1]; }
  }
  for (; e + 4 <= e1; e += 4) {
    int s[4];
#pragma unroll
    for (int u = 0; u < 4; ++u) s[u] = elist[e + u];
    f16x2 v[4];
#pragma unroll
    for (int u = 0; u < 4; ++u)
      v[u] = *(const f16x2*)(H + (size_t)s[u] * 128 + l * 2);
#pragma unroll
    for (int u = 0; u < 4; ++u) { a0 += (float)v[u][0]; a1 += (float)v[u][1]; }
  }
  for (; e < e1; ++e) {
    f16x2 v = *(const f16x2*)(H + (size_t)elist[e] * 128 + l * 2);
    a0 += (float)v[0]; a1 += (float)v[1];
  }
  float inv = 1.0f / (float)max(d, 1);
  f16x2 o;
  o[0] = (_Float16)(a0 * inv); o[1] = (_Float16)(a1 * inv);
  *(f16x2*)(M + (size_t)node * 128 + l * 2) = o;
}

// ---------------- gather64 + final add: out = F + mean(Y2[nbrs]) ----------
// Half-wave (32 lanes x f16x2) per node; writes f32 d_out directly.
__global__ __launch_bounds__(256) void gather64_add_kernel(
    const _Float16* __restrict__ Y2, const float* __restrict__ F,
    const int* __restrict__ offs, const int* __restrict__ deg,
    const int* __restrict__ elist, float* __restrict__ out) {
  int node = blockIdx.x * 8 + (threadIdx.x >> 5);
  if (node >= N) return;
  int l = threadIdx.x & 31;
  const int e0 = offs[node];
  const int d = deg[node];
  const int e1 = e0 + d;
  float a0 = 0.f, a1 = 0.f;
  int e = e0;
  for (; e + 16 <= e1; e += 16) {
    int s[16];
#pragma unroll
    for (int u = 0; u < 16; ++u) s[u] = elist[e + u];
    f16x2 v[16];
#pragma unroll
    for (int u = 0; u < 16; ++u)
      v[u] = *(const f16x2*)(Y2 + (size_t)s[u] * 64 + l * 2);
#pragma unroll
    for (int u = 0; u < 16; ++u) { a0 += (float)v[u][0]; a1 += (float)v[u][1]; }
  }
  for (; e + 4 <= e1; e += 4) {
    int s[4];
#pragma unroll
    for (int u = 0; u < 4; ++u) s[u] = elist[e + u];
    f16x2 v[4];
#pragma unroll
    for (int u = 0; u < 4; ++u)
      v[u] = *(const f16x2*)(Y2 + (size_t)s[u] * 64 + l * 2);
#pragma unroll
    for (int u = 0; u < 4; ++u) { a0 += (float)v[u][0]; a1 += (float)v[u][1]; }
  }
  for (; e < e1; ++e) {
    f16x2 v = *(const f16x2*)(Y2 + (size_t)elist[e] * 64 + l * 2);
    a0 += (float)v[0]; a1 += (float)v[1];
  }
  float inv = 1.0f / (float)max(d, 1);
  float2 f = ((const float2*)(F + (size_t)node * 64))[l];
  float2 o;
  o.x = f.x + a0 * inv;
  o.y = f.y + a1 * inv;
  ((float2*)(out + (size_t)node * 64))[l] = o;
}

// ---------------- MFMA GEMM (layers 0/1): out = [M|H]@[wl|wr]^T+b, relu,drop
// Wave tile 32 rows x 32 cols; 4 col-groups; 32 rows/block; K=256.
__global__ __launch_bounds__(256, 4) void mfma_gemm128_kernel(
    const _Float16* __restrict__ Mm, const _Float16* __restrict__ Hh,
    const _Float16* __restrict__ Wf, const float* __restrict__ bias,
    const float* __restrict__ U, _Float16* __restrict__ outp) {
  const int lane = threadIdx.x & 63;
  const int w = threadIdx.x >> 6;
  const int n16 = lane & 15;
  const int q = lane >> 4;
  const int rowbase = blockIdx.x * 32;
  const int colbase = w * 32;

  f32x4 acc[2][2];
#pragma unroll
  for (int h = 0; h < 2; ++h)
#pragma unroll
    for (int ct = 0; ct < 2; ++ct) acc[h][ct] = (f32x4){0.f, 0.f, 0.f, 0.f};

  int ar0 = min(rowbase + n16, N - 1);       // clamp feeds only discarded rows
  int ar1 = min(rowbase + 16 + n16, N - 1);
  const _Float16* pM0 = Mm + (size_t)ar0 * 128 + q * 8;
  const _Float16* pM1 = Mm + (size_t)ar1 * 128 + q * 8;
  const _Float16* pH0 = Hh + (size_t)ar0 * 128 + q * 8;
  const _Float16* pH1 = Hh + (size_t)ar1 * 128 + q * 8;

#pragma unroll
  for (int kb = 0; kb < 8; ++kb) {
    const int ko = (kb & 3) * 32;
    f16x8 a0 = *(const f16x8*)((kb < 4 ? pM0 : pH0) + ko);
    f16x8 a1 = *(const f16x8*)((kb < 4 ? pM1 : pH1) + ko);
#pragma unroll
    for (int ct = 0; ct < 2; ++ct) {
      const int ctg = w * 2 + ct;
      f16x8 b = *(const f16x8*)(Wf + ((size_t)(ctg * 8 + kb) * 64 + lane) * 8);
      acc[0][ct] = __builtin_amdgcn_mfma_f32_16x16x32_f16(a0, b, acc[0][ct], 0, 0, 0);
      acc[1][ct] = __builtin_amdgcn_mfma_f32_16x16x32_f16(a1, b, acc[1][ct], 0, 0, 0);
    }
  }

  // C/D layout: col = lane&15, row = (lane>>4)*4 + reg
#pragma unroll
  for (int h = 0; h < 2; ++h) {
#pragma unroll
    for (int ct = 0; ct < 2; ++ct) {
      const int col = colbase + ct * 16 + n16;
      const float bv = bias[col];
#pragma unroll
      for (int r = 0; r < 4; ++r) {
        int row = rowbase + h * 16 + q * 4 + r;
        if (row < N) {
          float v = fmaxf(acc[h][ct][r] + bv, 0.f);
          float u = U[(size_t)row * 128 + col];
          v *= (u >= 0.3f) ? (1.0f / 0.7f) : 0.0f;
          outp[(size_t)row * 128 + col] = (_Float16)v;
        }
      }
    }
  }
}

// ---------------- layer-2 Z GEMM: cols 0-63 -> Y2=H@wl2^T (f16);
//                  cols 64-127 -> F=H@wr2^T+bl2 (f32). K=128.
__global__ __launch_bounds__(256, 4) void mfma_gemmZ_kernel(
    const _Float16* __restrict__ Hh, const _Float16* __restrict__ Wf,
    const float* __restrict__ bl2, _Float16* __restrict__ Y2,
    float* __restrict__ F) {
  const int lane = threadIdx.x & 63;
  const int w = threadIdx.x >> 6;
  const int n16 = lane & 15;
  const int q = lane >> 4;
  const int rowbase = blockIdx.x * 32;
  const int colbase = w * 32;

  f32x4 acc[2][2];
#pragma unroll
  for (int h = 0; h < 2; ++h)
#pragma unroll
    for (int ct = 0; ct < 2; ++ct) acc[h][ct] = (f32x4){0.f, 0.f, 0.f, 0.f};

  int ar0 = min(rowbase + n16, N - 1);
  int ar1 = min(rowbase + 16 + n16, N - 1);
  const _Float16* pH0 = Hh + (size_t)ar0 * 128 + q * 8;
  const _Float16* pH1 = Hh + (size_t)ar1 * 128 + q * 8;

#pragma unroll
  for (int kb = 0; kb < 4; ++kb) {
    const int ko = kb * 32;
    f16x8 a0 = *(const f16x8*)(pH0 + ko);
    f16x8 a1 = *(const f16x8*)(pH1 + ko);
#pragma unroll
    for (int ct = 0; ct < 2; ++ct) {
      const int ctg = w * 2 + ct;
      f16x8 b = *(const f16x8*)(Wf + ((size_t)(ctg * 4 + kb) * 64 + lane) * 8);
      acc[0][ct] = __builtin_amdgcn_mfma_f32_16x16x32_f16(a0, b, acc[0][ct], 0, 0, 0);
      acc[1][ct] = __builtin_amdgcn_mfma_f32_16x16x32_f16(a1, b, acc[1][ct], 0, 0, 0);
    }
  }

#pragma unroll
  for (int h = 0; h < 2; ++h) {
#pragma unroll
    for (int ct = 0; ct < 2; ++ct) {
      const int col = colbase + ct * 16 + n16;
#pragma unroll
      for (int r = 0; r < 4; ++r) {
        int row = rowbase + h * 16 + q * 4 + r;
        if (row < N) {
          float v = acc[h][ct][r];
          if (col < 64) Y2[(size_t)row * 64 + col] = (_Float16)v;
          else F[(size_t)row * 64 + (col - 64)] = v + bl2[col - 64];
        }
      }
    }
  }
}

extern "C" void kernel_launch(void* const* d_in, const int* in_sizes, int n_in,
                              void* d_out, int out_size, void* d_ws, size_t ws_size,
                              hipStream_t stream) {
  const float* x   = (const float*)d_in[0];
  const float* u1  = (const float*)d_in[1];
  const float* u2  = (const float*)d_in[2];
  const float* wl0 = (const float*)d_in[3];
  const float* bl0 = (const float*)d_in[4];
  const float* wr0 = (const float*)d_in[5];
  const float* wl1 = (const float*)d_in[6];
  const float* bl1 = (const float*)d_in[7];
  const float* wr1 = (const float*)d_in[8];
  const float* wl2 = (const float*)d_in[9];
  const float* bl2 = (const float*)d_in[10];
  const float* wr2 = (const float*)d_in[11];
  const int* edge  = (const int*)d_in[12];
  const int* src = edge;
  const int* dst = edge + E;

  // workspace layout
  _Float16* HA  = (_Float16*)d_ws;                 // N x 128 f16
  _Float16* HB  = HA + (size_t)N * 128;            // N x 128 f16
  _Float16* M16 = HB + (size_t)N * 128;            // N x 128 f16 (M, then Y2)
  float* F      = (float*)(M16 + (size_t)N * 128); // N x 64 f32
  int* offs     = (int*)(F + (size_t)N * 64);      // N
  int* deg      = offs + N;                        // N
  int* elist    = deg + N;                         // NBUCK*SLOT (padded)
  unsigned* T   = (unsigned*)(elist + NBUCK * SLOT);
  int* bcur     = (int*)(T + NBUCK * SLOT);        // NBUCK
  uintptr_t p = (uintptr_t)(bcur + NBUCK);
  p = (p + 15) & ~(uintptr_t)15;
  _Float16* wf0 = (_Float16*)p;                    // 8*8*512
  _Float16* wf1 = wf0 + 8 * 8 * 512;
  _Float16* wfZ = wf1 + 8 * 8 * 512;               // 8*4*512

  // 1) setup: convert + 3 wfrag tables + bcur init
  setup_kernel<<<CONVB + 321, 256, 0, stream>>>(
      x, wl0, wr0, wl1, wr1, wl2, wr2, HA, wf0, wf1, wfZ, bcur);
  // 2-3) CSR build
  bucket_scatter_kernel<<<NEB, 256, 0, stream>>>(src, dst, bcur, T);
  bucket_place_kernel<<<NBUCK, 256, 0, stream>>>(T, bcur, offs, deg, elist);

  const int GG128 = (N + 3) / 4;       // wave per node
  const int GG64  = (N + 7) / 8;       // half-wave per node
  const int GM    = (N + 31) / 32;     // 32 rows/block

  // ---- Layer 0 ----
  gather128_kernel<<<GG128, 256, 0, stream>>>(HA, offs, deg, elist, M16);
  mfma_gemm128_kernel<<<GM, 256, 0, stream>>>(M16, HA, wf0, bl0, u1, HB);
  // ---- Layer 1 ----
  gather128_kernel<<<GG128, 256, 0, stream>>>(HB, offs, deg, elist, M16);
  mfma_gemm128_kernel<<<GM, 256, 0, stream>>>(M16, HB, wf1, bl1, u2, HA);
  // ---- Layer 2 ----
  mfma_gemmZ_kernel<<<GM, 256, 0, stream>>>(HA, wfZ, bl2, M16, F);
  gather64_add_kernel<<<GG64, 256, 0, stream>>>(M16, F, offs, deg, elist,
                                                (float*)d_out);
}